// Round 13
// baseline (305.928 us; speedup 1.0000x reference)
//
#include <hip/hip_runtime.h>

typedef __bf16 bf16;
typedef __bf16 bf16x4 __attribute__((ext_vector_type(4)));
typedef __bf16 bf16x8 __attribute__((ext_vector_type(8)));
typedef float  f32x4  __attribute__((ext_vector_type(4)));

#define F32X4_ZERO ((f32x4){0.f, 0.f, 0.f, 0.f})

__device__ __forceinline__ f32x4 mfma16(bf16x8 a, bf16x8 b, f32x4 c) {
  return __builtin_amdgcn_mfma_f32_16x16x32_bf16(a, b, c, 0, 0, 0);
}

__device__ __forceinline__ void gld16(const void* g, void* l) {
  // async global->LDS, 16B/lane. LDS dest = wave-uniform base + lane*16.
  __builtin_amdgcn_global_load_lds((const __attribute__((address_space(1))) void*)g,
                                   (__attribute__((address_space(3))) void*)l, 16, 0, 0);
}

__device__ __forceinline__ float gelu_f(float u) {
  return 0.5f * u * (1.0f + erff(u * 0.70710678118654752f));
}

// Swizzled fragment read from a [row][128B] LDS tile staged with pre-swizzled
// source (chunk = 8 rows x 128B; slot s of row r holds logical col s^(r&7)).
__device__ __forceinline__ bf16x8 frag_ld(const bf16* base, int row, int c16) {
  return *(const bf16x8*)((const char*)base + row * 128 + (((c16) ^ (row & 7)) << 4));
}

// ---------------------------------------------------------------- transpose
__global__ void transpose2(const float* __restrict__ src, size_t sBatch, int sStride,
                           bf16* __restrict__ dst, size_t dBatch, int dStride) {
  __shared__ bf16 t[32][33];
  src += (size_t)blockIdx.z * sBatch;
  dst += (size_t)blockIdx.z * dBatch;
  int c0 = blockIdx.x * 32, r0 = blockIdx.y * 32;
#pragma unroll
  for (int i = 0; i < 4; i++) {
    int r = threadIdx.y + i * 8;
    t[r][threadIdx.x] = (bf16)src[(size_t)(r0 + r) * sStride + c0 + threadIdx.x];
  }
  __syncthreads();
#pragma unroll
  for (int i = 0; i < 4; i++) {
    int c = threadIdx.y + i * 8;
    dst[(size_t)(c0 + c) * dStride + r0 + threadIdx.x] = t[threadIdx.x][c];
  }
}

// ---------------------------------------------------------------- layernorm
__global__ __launch_bounds__(256) void ln_rows(const float* __restrict__ in,
                                               const float* __restrict__ gam,
                                               const float* __restrict__ bet,
                                               bf16* __restrict__ out) {
  int row = blockIdx.x, tid = threadIdx.x;
  f32x4 x = *(const f32x4*)(in + (size_t)row * 1024 + tid * 4);
  float s = 0.f, q = 0.f;
#pragma unroll
  for (int j = 0; j < 4; j++) { s += x[j]; q += x[j] * x[j]; }
#pragma unroll
  for (int o = 1; o < 64; o <<= 1) {
    s += __shfl_xor(s, o, 64);
    q += __shfl_xor(q, o, 64);
  }
  __shared__ float red[8];
  if ((tid & 63) == 0) { red[(tid >> 6) * 2] = s; red[(tid >> 6) * 2 + 1] = q; }
  __syncthreads();
  s = red[0] + red[2] + red[4] + red[6];
  q = red[1] + red[3] + red[5] + red[7];
  float mean = s * (1.f / 1024.f);
  float var  = q * (1.f / 1024.f) - mean * mean;
  float inv  = rsqrtf(var + 1e-6f);
  bf16x4 o;
#pragma unroll
  for (int j = 0; j < 4; j++) {
    int c = tid * 4 + j;
    o[j] = (bf16)((x[j] - mean) * inv * gam[c] + bet[c]);
  }
  *(bf16x4*)(out + (size_t)row * 1024 + tid * 4) = o;
}

// ---------------------------------------------------------------- QKV GEMM
// x1[4096][1024](bf16) @ WT[1024][1024] + bias. 128x128 tile, BK=64, 2-phase,
// XOR-swizzled LDS, XCD-rectangle block swizzle (each XCD: 4 M-rows x 8 N-cols).
__global__ __launch_bounds__(256) void qkv_gemm(
    const bf16* __restrict__ x1,
    const bf16* __restrict__ WqT, const bf16* __restrict__ WkT, const bf16* __restrict__ WvT,
    const float* __restrict__ bq, const float* __restrict__ bk, const float* __restrict__ bv,
    bf16* __restrict__ qo, bf16* __restrict__ ko, bf16* __restrict__ vto) {
  int tid = threadIdx.x, lane = tid & 63, wv = tid >> 6;
  int z = blockIdx.z;
  const bf16* BT; const float* bias;
  if (z == 0)      { BT = WqT; bias = bq; }
  else if (z == 1) { BT = WkT; bias = bk; }
  else             { BT = WvT; bias = bv; }
  // XCD swizzle: linear id (x + 8y) -> xcd owns rows 4*xcd..+3, all 8 cols.
  int bid = blockIdx.x + (blockIdx.y << 3);
  int xcd = bid & 7, idx = bid >> 3;
  int m0 = (xcd * 4 + (idx >> 3)) * 128, n0 = (idx & 7) * 128;
  int wrow = (wv >> 1) * 64, wcol = (wv & 1) * 64;
  __shared__ __align__(16) bf16 lA[2][128 * 64];
  __shared__ __align__(16) bf16 lB[2][128 * 64];
  f32x4 acc[4][4];
#pragma unroll
  for (int a = 0; a < 4; a++)
#pragma unroll
    for (int n = 0; n < 4; n++) acc[a][n] = F32X4_ZERO;

  int cbs = ((lane & 7) ^ (lane >> 3)) * 16;   // pre-swizzled source byte col
  auto stage = [&](int buf, int k0) {
#pragma unroll
    for (int s = 0; s < 4; s++) {
      int c = s * 4 + wv;                 // 16 chunks of 1KB (8 rows x 128B)
      int row = c * 8 + (lane >> 3);
      gld16((const char*)x1 + ((size_t)(m0 + row) * 1024 + k0) * 2 + cbs,
            (char*)lA[buf] + c * 1024);
      gld16((const char*)BT + ((size_t)(n0 + row) * 1024 + k0) * 2 + cbs,
            (char*)lB[buf] + c * 1024);
    }
  };

  stage(0, 0);
  __syncthreads();
  for (int t = 0; t < 16; t++) {
    int cur = t & 1;
    if (t < 15) stage(cur ^ 1, (t + 1) * 64);
#pragma unroll
    for (int kc = 0; kc < 2; kc++) {
      int c16 = kc * 4 + (lane >> 4);
      bf16x8 af[4], bfr[4];
#pragma unroll
      for (int mf = 0; mf < 4; mf++)
        af[mf] = frag_ld(lA[cur], wrow + mf * 16 + (lane & 15), c16);
#pragma unroll
      for (int nf = 0; nf < 4; nf++)
        bfr[nf] = frag_ld(lB[cur], wcol + nf * 16 + (lane & 15), c16);
#pragma unroll
      for (int mf = 0; mf < 4; mf++)
#pragma unroll
        for (int nf = 0; nf < 4; nf++)
          acc[mf][nf] = mfma16(af[mf], bfr[nf], acc[mf][nf]);
    }
    __syncthreads();
  }
#pragma unroll
  for (int mf = 0; mf < 4; mf++)
#pragma unroll
    for (int nf = 0; nf < 4; nf++)
#pragma unroll
      for (int i = 0; i < 4; i++) {
        int row  = m0 + wrow + mf * 16 + ((lane >> 4) << 2) + i;
        int ncol = n0 + wcol + nf * 16 + (lane & 15);
        int bb = row >> 10, s = row & 1023, head = ncol >> 6, d = ncol & 63;
        size_t bh = (size_t)bb * 16 + head;
        float v = acc[mf][nf][i] + bias[ncol];
        if (z == 0)      qo[(bh * 1024 + s) * 64 + d] = (bf16)(v * 0.125f);
        else if (z == 1) ko[(bh * 1024 + s) * 64 + d] = (bf16)v;
        else             vto[(bh * 64 + d) * 1024 + s] = (bf16)v;
      }
}

// ---------------------------------------------------------------- attention
// GEMM-style pipelined flash attention (r9 structure, unchanged).
__global__ __launch_bounds__(512) void attn_flash(
    const bf16* __restrict__ qb, const bf16* __restrict__ kb, const bf16* __restrict__ vtb,
    const int* __restrict__ mask, bf16* __restrict__ attnC) {
  int tid = threadIdx.x, lane = tid & 63, wv = tid >> 6;  // 8 waves
  int wgid = blockIdx.x;
  int nid  = (wgid & 7) * 64 + (wgid >> 3);
  int qblk = nid & 7, h = (nid >> 3) & 15, b = nid >> 7;
  int qrow0 = qblk * 128 + wv * 16;

  __shared__ float smask[1024];
  __shared__ __align__(16) bf16 kt[2][64 * 64];
  __shared__ __align__(16) bf16 vt[2][64 * 64];
  __shared__ __align__(16) bf16 pb[8][16][72];
  for (int i = tid; i < 1024; i += 512) smask[i] = mask[b * 1024 + i] ? 0.f : -1e9f;

  size_t bh = (size_t)b * 16 + h;
  const bf16* qp = qb + (bh * 1024 + qrow0) * 64;
  bf16x8 qa[2];
#pragma unroll
  for (int kc = 0; kc < 2; kc++)
    qa[kc] = *(const bf16x8*)(qp + (lane & 15) * 64 + kc * 32 + (lane >> 4) * 8);

  const bf16* kp = kb + bh * 1024 * 64;
  const bf16* vp = vtb + bh * 64 * 1024;
  bf16* myp = &pb[wv][0][0];

  bf16x8 vone;
#pragma unroll
  for (int j = 0; j < 8; j++) vone[j] = (bf16)1.0f;

  f32x4 ssum = F32X4_ZERO;
  f32x4 oacc[4];
#pragma unroll
  for (int i = 0; i < 4; i++) oacc[i] = F32X4_ZERO;

  int srl = lane >> 3;
  int sbc = ((lane & 7) ^ srl) * 16;
  auto stage = [&](int buf, int t2) {
    int key0n = t2 * 64;
#pragma unroll
    for (int j = 0; j < 2; j++) {
      int c = wv * 2 + j;
      if (c < 8) {
        int row = c * 8 + srl;
        gld16((const char*)kp + ((size_t)(key0n + row) * 64) * 2 + sbc,
              (char*)kt[buf] + c * 1024);
      } else {
        int row = (c - 8) * 8 + srl;
        gld16((const char*)vp + ((size_t)row * 1024 + key0n) * 2 + sbc,
              (char*)vt[buf] + (c - 8) * 1024);
      }
    }
  };

  stage(0, 0);
  __syncthreads();

  for (int t = 0; t < 16; t++) {
    int cur = t & 1;
    if (t < 15) stage(cur ^ 1, t + 1);
    const bf16* kcur = kt[cur];
    const bf16* vcur = vt[cur];
    int key0 = t * 64;
    f32x4 st[4];
    __builtin_amdgcn_s_setprio(1);
#pragma unroll
    for (int nt = 0; nt < 4; nt++) {
      st[nt] = F32X4_ZERO;
#pragma unroll
      for (int kc = 0; kc < 2; kc++) {
        bf16x8 kf = frag_ld(kcur, nt * 16 + (lane & 15), kc * 4 + (lane >> 4));
        st[nt] = mfma16(qa[kc], kf, st[nt]);
      }
    }
    __builtin_amdgcn_s_setprio(0);
#pragma unroll
    for (int nt = 0; nt < 4; nt++) {
      float ms = smask[key0 + nt * 16 + (lane & 15)] - 8.0f;
#pragma unroll
      for (int i = 0; i < 4; i++) st[nt][i] = __expf(st[nt][i] + ms);
    }
#pragma unroll
    for (int nt = 0; nt < 4; nt++)
#pragma unroll
      for (int i = 0; i < 4; i++)
        myp[((lane >> 4) * 4 + i) * 72 + nt * 16 + (lane & 15)] = (bf16)st[nt][i];
    __builtin_amdgcn_s_setprio(1);
#pragma unroll
    for (int kc = 0; kc < 2; kc++) {
      bf16x8 pa = *(const bf16x8*)(myp + (lane & 15) * 72 + kc * 32 + (lane >> 4) * 8);
      ssum = mfma16(pa, vone, ssum);
#pragma unroll
      for (int dn = 0; dn < 4; dn++) {
        bf16x8 vf = frag_ld(vcur, dn * 16 + (lane & 15), kc * 4 + (lane >> 4));
        oacc[dn] = mfma16(pa, vf, oacc[dn]);
      }
    }
    __builtin_amdgcn_s_setprio(0);
    __syncthreads();
  }
#pragma unroll
  for (int i = 0; i < 4; i++) {
    float inv = 1.0f / ssum[i];
    int row = qrow0 + ((lane >> 4) << 2) + i;
#pragma unroll
    for (int dn = 0; dn < 4; dn++)
      attnC[(size_t)(b * 1024 + row) * 1024 + h * 64 + dn * 16 + (lane & 15)] =
          (bf16)(oacc[dn][i] * inv);
  }
}

// ---------------------------------------------------------------- 256^2 GEMM (GELU)
// BM=BN=256, BK=64, 8 waves, 2-phase, XOR-swizzled LDS, compile-time K=1024.
// XCD-rectangle swizzle: each XCD owns a 4-row x 8-col rect of the 16x16 grid.
__global__ __launch_bounds__(512) void gemm256_gelu(
    const bf16* __restrict__ A, const bf16* __restrict__ BT, const float* __restrict__ bias,
    int N, bf16* __restrict__ outb) {
  int tid = threadIdx.x, lane = tid & 63, wv = tid >> 6;  // 8 waves
  int bid = blockIdx.x + (blockIdx.y << 4);   // linear 0..255; HW xcd = bid&7
  int xcd = bid & 7, idx = bid >> 3;          // idx 0..31
  int m0 = ((xcd >> 1) * 4 + (idx >> 3)) * 256;  // rows 4*(xcd>>1)+0..3
  int n0 = ((xcd & 1) * 8 + (idx & 7)) * 256;    // cols 8*(xcd&1)+0..7
  int wrow = (wv >> 2) * 128, wcol = (wv & 3) * 64;
  __shared__ __align__(16) bf16 lA[2][256 * 64];
  __shared__ __align__(16) bf16 lB[2][256 * 64];
  f32x4 acc[8][4];
#pragma unroll
  for (int a = 0; a < 8; a++)
#pragma unroll
    for (int n = 0; n < 4; n++) acc[a][n] = F32X4_ZERO;

  int cbs = ((lane & 7) ^ (lane >> 3)) * 16;
  auto stage = [&](int buf, int k0) {
#pragma unroll
    for (int s = 0; s < 4; s++) {
      int c = s * 8 + wv;                 // 32 chunks of 1KB (8 rows x 128B)
      int row = c * 8 + (lane >> 3);
      gld16((const char*)A  + ((size_t)(m0 + row) * 1024 + k0) * 2 + cbs,
            (char*)lA[buf] + c * 1024);
      gld16((const char*)BT + ((size_t)(n0 + row) * 1024 + k0) * 2 + cbs,
            (char*)lB[buf] + c * 1024);
    }
  };

  stage(0, 0);
  __syncthreads();
#pragma unroll 1
  for (int t = 0; t < 16; t++) {
    int cur = t & 1;
    if (t < 15) stage(cur ^ 1, (t + 1) * 64);
#pragma unroll
    for (int kc = 0; kc < 2; kc++) {
      int c16 = kc * 4 + (lane >> 4);
      bf16x8 bfr[4];
#pragma unroll
      for (int nf = 0; nf < 4; nf++)
        bfr[nf] = frag_ld(lB[cur], wcol + nf * 16 + (lane & 15), c16);
#pragma unroll
      for (int mf = 0; mf < 8; mf++) {
        bf16x8 af = frag_ld(lA[cur], wrow + mf * 16 + (lane & 15), c16);
#pragma unroll
        for (int nf = 0; nf < 4; nf++)
          acc[mf][nf] = mfma16(af, bfr[nf], acc[mf][nf]);
      }
    }
    __syncthreads();
  }
#pragma unroll
  for (int mf = 0; mf < 8; mf++)
#pragma unroll
    for (int nf = 0; nf < 4; nf++)
#pragma unroll
      for (int i = 0; i < 4; i++) {
        int row = m0 + wrow + mf * 16 + ((lane >> 4) << 2) + i;
        int col = n0 + wcol + nf * 16 + (lane & 15);
        float u = acc[mf][nf][i] + bias[col];
        outb[(size_t)row * N + col] = (bf16)gelu_f(u);
      }
}

// ---------------------------------------------------------------- big GEMM
// 128x128, BK=64, compile-time K, 2-phase, XOR-swizzled LDS, XCD swizzle
// (grid must be (8, M/128): each XCD owns rows 4*xcd..+3 across all 8 cols).
enum { EPI_WO = 0, EPI_GELU = 1, EPI_ACC0 = 2, EPI_ACC = 3, EPI_FINAL = 4 };

template <int EPI, int K>
__global__ __launch_bounds__(256) void gemm_bt(
    const bf16* __restrict__ A, const bf16* __restrict__ BT, const float* __restrict__ bias,
    int N,
    const float* __restrict__ resid,  // EPI_WO / EPI_FINAL: f32 residual
    float* __restrict__ facc,         // EPI_ACC0/ACC: write/accum; EPI_FINAL: read
    bf16* __restrict__ outb,          // EPI_GELU
    float* __restrict__ outf) {       // EPI_WO / EPI_FINAL
  int tid = threadIdx.x, lane = tid & 63, wv = tid >> 6;
  int bid = blockIdx.x + (blockIdx.y << 3);
  int xcd = bid & 7, idx = bid >> 3;
  int m0 = (xcd * 4 + (idx >> 3)) * 128, n0 = (idx & 7) * 128;
  int wrow = (wv >> 1) * 64, wcol = (wv & 1) * 64;
  __shared__ __align__(16) bf16 lA[2][128 * 64];
  __shared__ __align__(16) bf16 lB[2][128 * 64];
  f32x4 acc[4][4];
#pragma unroll
  for (int a = 0; a < 4; a++)
#pragma unroll
    for (int n = 0; n < 4; n++) acc[a][n] = F32X4_ZERO;

  int cbs = ((lane & 7) ^ (lane >> 3)) * 16;
  auto stage = [&](int buf, int k0) {
#pragma unroll
    for (int s = 0; s < 4; s++) {
      int c = s * 4 + wv;
      int row = c * 8 + (lane >> 3);
      gld16((const char*)A  + ((size_t)(m0 + row) * K + k0) * 2 + cbs,
            (char*)lA[buf] + c * 1024);
      gld16((const char*)BT + ((size_t)(n0 + row) * K + k0) * 2 + cbs,
            (char*)lB[buf] + c * 1024);
    }
  };

  constexpr int nk = K >> 6;
  stage(0, 0);
  __syncthreads();
#pragma unroll 1
  for (int t = 0; t < nk; t++) {
    int cur = t & 1;
    if (t + 1 < nk) stage(cur ^ 1, (t + 1) * 64);
#pragma unroll
    for (int kc = 0; kc < 2; kc++) {
      int c16 = kc * 4 + (lane >> 4);
      bf16x8 af[4], bfr[4];
#pragma unroll
      for (int mf = 0; mf < 4; mf++)
        af[mf] = frag_ld(lA[cur], wrow + mf * 16 + (lane & 15), c16);
#pragma unroll
      for (int nf = 0; nf < 4; nf++)
        bfr[nf] = frag_ld(lB[cur], wcol + nf * 16 + (lane & 15), c16);
#pragma unroll
      for (int mf = 0; mf < 4; mf++)
#pragma unroll
        for (int nf = 0; nf < 4; nf++)
          acc[mf][nf] = mfma16(af[mf], bfr[nf], acc[mf][nf]);
    }
    __syncthreads();
  }
#pragma unroll
  for (int mf = 0; mf < 4; mf++)
#pragma unroll
    for (int nf = 0; nf < 4; nf++)
#pragma unroll
      for (int i = 0; i < 4; i++) {
        int row = m0 + wrow + mf * 16 + ((lane >> 4) << 2) + i;
        int col = n0 + wcol + nf * 16 + (lane & 15);
        size_t idx2 = (size_t)row * N + col;
        float v = acc[mf][nf][i];
        if constexpr (EPI == EPI_WO) {
          outf[idx2] = v + bias[col] + resid[idx2];
        } else if constexpr (EPI == EPI_GELU) {
          outb[idx2] = (bf16)gelu_f(v + bias[col]);
        } else if constexpr (EPI == EPI_ACC0) {
          facc[idx2] = v;
        } else if constexpr (EPI == EPI_ACC) {
          facc[idx2] += v;
        } else {  // EPI_FINAL
          outf[idx2] = facc[idx2] + v + bias[col] + resid[idx2];
        }
      }
}

// ---------------------------------------------------------------- launch
extern "C" void kernel_launch(void* const* d_in, const int* in_sizes, int n_in,
                              void* d_out, int out_size, void* d_ws, size_t ws_size,
                              hipStream_t stream) {
  const float* hidden = (const float*)d_in[0];
  const int*   mask   = (const int*)d_in[1];
  const float* Wq = (const float*)d_in[2];
  const float* bq = (const float*)d_in[3];
  const float* Wk = (const float*)d_in[4];
  const float* bk = (const float*)d_in[5];
  const float* Wv = (const float*)d_in[6];
  const float* bv = (const float*)d_in[7];
  const float* Wo = (const float*)d_in[8];
  const float* bo = (const float*)d_in[9];
  const float* ln1g = (const float*)d_in[10];
  const float* ln1b = (const float*)d_in[11];
  const float* ln2g = (const float*)d_in[12];
  const float* ln2b = (const float*)d_in[13];
  const float* W1 = (const float*)d_in[14];
  const float* b1 = (const float*)d_in[15];
  const float* W2 = (const float*)d_in[16];
  const float* b2 = (const float*)d_in[17];
  float* out = (float*)d_out;

  char* ws = (char*)d_ws;
  const size_t MB = 1ull << 20;
  dim3 tb(32, 8);
  const size_t HB = 64 * 1024;  // per-head weight elements

  if (ws_size >= 96 * MB) {
    // ---------------- simple path (88 MB) ----------------
    bf16* x1    = (bf16*)(ws + 0 * MB);   // -> attnC -> x2
    bf16* attnC = x1;
    bf16* x2    = x1;
    bf16* qbuf  = (bf16*)(ws + 8 * MB);   // -> W1T
    bf16* W1T   = qbuf;
    bf16* kbuf  = (bf16*)(ws + 16 * MB);  // -> W2T
    bf16* W2T   = kbuf;
    bf16* vtbuf = (bf16*)(ws + 24 * MB);
    float* hbuf = (float*)(ws + 32 * MB); // 16 MB f32
    bf16* WqT   = (bf16*)(ws + 48 * MB);
    bf16* WkT   = (bf16*)(ws + 50 * MB);
    bf16* WvT   = (bf16*)(ws + 52 * MB);
    bf16* WoT   = (bf16*)(ws + 54 * MB);
    bf16* gbuf  = (bf16*)(ws + 56 * MB);  // 32 MB

    transpose2<<<dim3(2, 32, 16), tb, 0, stream>>>(Wq, HB, 64, WqT, HB, 1024);
    transpose2<<<dim3(2, 32, 16), tb, 0, stream>>>(Wk, HB, 64, WkT, HB, 1024);
    transpose2<<<dim3(2, 32, 16), tb, 0, stream>>>(Wv, HB, 64, WvT, HB, 1024);
    transpose2<<<dim3(32, 32, 1), tb, 0, stream>>>(Wo, 0, 1024, WoT, 0, 1024);
    ln_rows<<<4096, 256, 0, stream>>>(hidden, ln1g, ln1b, x1);
    qkv_gemm<<<dim3(8, 32, 3), 256, 0, stream>>>(x1, WqT, WkT, WvT, bq, bk, bv,
                                                 qbuf, kbuf, vtbuf);
    attn_flash<<<512, 512, 0, stream>>>(qbuf, kbuf, vtbuf, mask, attnC);
    gemm_bt<EPI_WO, 1024><<<dim3(8, 32), 256, 0, stream>>>(attnC, WoT, bo, 1024,
                                                           hidden, nullptr, nullptr, hbuf);
    ln_rows<<<4096, 256, 0, stream>>>(hbuf, ln2g, ln2b, x2);
    transpose2<<<dim3(128, 32, 1), tb, 0, stream>>>(W1, 0, 4096, W1T, 0, 1024);
    transpose2<<<dim3(32, 128, 1), tb, 0, stream>>>(W2, 0, 1024, W2T, 0, 4096);
    gemm256_gelu<<<dim3(16, 16), 512, 0, stream>>>(x2, W1T, b1, 4096, gbuf);
    gemm_bt<EPI_WO, 4096><<<dim3(8, 32), 256, 0, stream>>>(gbuf, W2T, b2, 1024,
                                                           hbuf, nullptr, nullptr, out);
  } else {
    // ---------------- chunked path (56 MB) ----------------
    bf16* x1     = (bf16*)(ws + 0 * MB);   // -> attnC -> x2
    bf16* attnC  = x1;
    bf16* x2     = x1;
    bf16* qbuf   = (bf16*)(ws + 8 * MB);   // -> W1Tc/W2Tc/gchunk
    bf16* W1Tc   = (bf16*)(ws + 8 * MB);   // [512][1024] 1 MB
    bf16* W2Tc   = (bf16*)(ws + 10 * MB);  // [1024][512] 1 MB
    bf16* gchunk = (bf16*)(ws + 12 * MB);  // [4096][512] 4 MB
    bf16* kbuf   = (bf16*)(ws + 16 * MB);  // -> hbuf (with vtbuf)
    bf16* vtbuf  = (bf16*)(ws + 24 * MB);
    float* hbuf  = (float*)(ws + 16 * MB); // 16 MB f32
    bf16* WqT    = (bf16*)(ws + 32 * MB);
    bf16* WkT    = (bf16*)(ws + 34 * MB);
    bf16* WvT    = (bf16*)(ws + 36 * MB);
    bf16* WoT    = (bf16*)(ws + 38 * MB);
    float* outacc = (float*)(ws + 40 * MB); // 16 MB f32

    transpose2<<<dim3(2, 32, 16), tb, 0, stream>>>(Wq, HB, 64, WqT, HB, 1024);
    transpose2<<<dim3(2, 32, 16), tb, 0, stream>>>(Wk, HB, 64, WkT, HB, 1024);
    transpose2<<<dim3(2, 32, 16), tb, 0, stream>>>(Wv, HB, 64, WvT, HB, 1024);
    transpose2<<<dim3(32, 32, 1), tb, 0, stream>>>(Wo, 0, 1024, WoT, 0, 1024);
    ln_rows<<<4096, 256, 0, stream>>>(hidden, ln1g, ln1b, x1);
    qkv_gemm<<<dim3(8, 32, 3), 256, 0, stream>>>(x1, WqT, WkT, WvT, bq, bk, bv,
                                                 qbuf, kbuf, vtbuf);
    attn_flash<<<512, 512, 0, stream>>>(qbuf, kbuf, vtbuf, mask, attnC);
    gemm_bt<EPI_WO, 1024><<<dim3(8, 32), 256, 0, stream>>>(attnC, WoT, bo, 1024,
                                                           hidden, nullptr, nullptr, hbuf);
    ln_rows<<<4096, 256, 0, stream>>>(hbuf, ln2g, ln2b, x2);

    for (int c = 0; c < 8; c++) {
      transpose2<<<dim3(16, 32, 1), tb, 0, stream>>>(W1 + c * 512, 0, 4096,
                                                     W1Tc, 0, 1024);
      transpose2<<<dim3(32, 16, 1), tb, 0, stream>>>(W2 + (size_t)c * 512 * 1024, 0, 1024,
                                                     W2Tc, 0, 512);
      gemm_bt<EPI_GELU, 1024><<<dim3(4, 32), 256, 0, stream>>>(x2, W1Tc, b1 + c * 512,
                                                               512,
                                                               nullptr, nullptr, gchunk, nullptr);
      if (c == 0)
        gemm_bt<EPI_ACC0, 512><<<dim3(8, 32), 256, 0, stream>>>(gchunk, W2Tc, b2, 1024,
                                                                nullptr, outacc, nullptr, nullptr);
      else if (c < 7)
        gemm_bt<EPI_ACC, 512><<<dim3(8, 32), 256, 0, stream>>>(gchunk, W2Tc, b2, 1024,
                                                               nullptr, outacc, nullptr, nullptr);
      else
        gemm_bt<EPI_FINAL, 512><<<dim3(8, 32), 256, 0, stream>>>(gchunk, W2Tc, b2, 1024,
                                                                 hbuf, outacc, nullptr, out);
    }
  }

  (void)in_sizes; (void)n_in; (void)out_size;
}

// Round 14
// 263.338 us; speedup vs baseline: 1.1617x; 1.1617x over previous
//
#include <hip/hip_runtime.h>

typedef __bf16 bf16;
typedef __bf16 bf16x4 __attribute__((ext_vector_type(4)));
typedef __bf16 bf16x8 __attribute__((ext_vector_type(8)));
typedef float  f32x4  __attribute__((ext_vector_type(4)));

#define F32X4_ZERO ((f32x4){0.f, 0.f, 0.f, 0.f})

__device__ __forceinline__ f32x4 mfma16(bf16x8 a, bf16x8 b, f32x4 c) {
  return __builtin_amdgcn_mfma_f32_16x16x32_bf16(a, b, c, 0, 0, 0);
}

__device__ __forceinline__ void gld16(const void* g, void* l) {
  __builtin_amdgcn_global_load_lds((const __attribute__((address_space(1))) void*)g,
                                   (__attribute__((address_space(3))) void*)l, 16, 0, 0);
}

__device__ __forceinline__ float gelu_f(float u) {
  return 0.5f * u * (1.0f + erff(u * 0.70710678118654752f));
}

// ---- BK=64 tile helpers (old 2-phase engine; chunked path + attention) ----
__device__ __forceinline__ bf16x8 frag_ld(const bf16* base, int row, int c16) {
  return *(const bf16x8*)((const char*)base + row * 128 + (((c16) ^ (row & 7)) << 4));
}

// ---- BK=32 tile helpers (counted-vmcnt pipeline engine) ----
// row = 64B; chunk = 1KB = 16 rows. phys slot = c16 ^ ((row>>1)&3)  (2-way free).
__device__ __forceinline__ bf16x8 frag_ld32(const bf16* base, int row, int c16) {
  return *(const bf16x8*)((const char*)base + row * 64 + ((c16 ^ ((row >> 1) & 3)) << 4));
}
// counted wait + barrier, un-reorderable
#define WAITB(N) asm volatile("s_waitcnt vmcnt(" #N ")\ns_barrier" ::: "memory")

// ---------------------------------------------------------------- transpose
__global__ void transpose2(const float* __restrict__ src, size_t sBatch, int sStride,
                           bf16* __restrict__ dst, size_t dBatch, int dStride) {
  __shared__ bf16 t[32][33];
  src += (size_t)blockIdx.z * sBatch;
  dst += (size_t)blockIdx.z * dBatch;
  int c0 = blockIdx.x * 32, r0 = blockIdx.y * 32;
#pragma unroll
  for (int i = 0; i < 4; i++) {
    int r = threadIdx.y + i * 8;
    t[r][threadIdx.x] = (bf16)src[(size_t)(r0 + r) * sStride + c0 + threadIdx.x];
  }
  __syncthreads();
#pragma unroll
  for (int i = 0; i < 4; i++) {
    int c = threadIdx.y + i * 8;
    dst[(size_t)(c0 + c) * dStride + r0 + threadIdx.x] = t[threadIdx.x][c];
  }
}

// ---------------------------------------------------------------- layernorm
__global__ __launch_bounds__(256) void ln_rows(const float* __restrict__ in,
                                               const float* __restrict__ gam,
                                               const float* __restrict__ bet,
                                               bf16* __restrict__ out) {
  int row = blockIdx.x, tid = threadIdx.x;
  f32x4 x = *(const f32x4*)(in + (size_t)row * 1024 + tid * 4);
  float s = 0.f, q = 0.f;
#pragma unroll
  for (int j = 0; j < 4; j++) { s += x[j]; q += x[j] * x[j]; }
#pragma unroll
  for (int o = 1; o < 64; o <<= 1) {
    s += __shfl_xor(s, o, 64);
    q += __shfl_xor(q, o, 64);
  }
  __shared__ float red[8];
  if ((tid & 63) == 0) { red[(tid >> 6) * 2] = s; red[(tid >> 6) * 2 + 1] = q; }
  __syncthreads();
  s = red[0] + red[2] + red[4] + red[6];
  q = red[1] + red[3] + red[5] + red[7];
  float mean = s * (1.f / 1024.f);
  float var  = q * (1.f / 1024.f) - mean * mean;
  float inv  = rsqrtf(var + 1e-6f);
  bf16x4 o;
#pragma unroll
  for (int j = 0; j < 4; j++) {
    int c = tid * 4 + j;
    o[j] = (bf16)((x[j] - mean) * inv * gam[c] + bet[c]);
  }
  *(bf16x4*)(out + (size_t)row * 1024 + tid * 4) = o;
}

// ============================================================ pipe engine
// 4-slot LDS, BK=32, depth-3 prefetch, counted vmcnt(8/4/0) + raw barrier.
// Stage = 4 gld16/thread (uniform across 128/256 variants).

// ---------------------------------------------------------------- FFN1: 256^2
__global__ __launch_bounds__(512) void pipe256_gelu(
    const bf16* __restrict__ A, const bf16* __restrict__ BT, const float* __restrict__ bias,
    int N, bf16* __restrict__ outb) {
  int tid = threadIdx.x, lane = tid & 63, wv = tid >> 6;  // 8 waves
  int bid = blockIdx.x + (blockIdx.y << 4);
  int xcd = bid & 7, idx = bid >> 3;
  int m0 = ((xcd >> 1) * 4 + (idx >> 3)) * 256;
  int n0 = ((xcd & 1) * 8 + (idx & 7)) * 256;
  int wrow = (wv >> 2) * 128, wcol = (wv & 3) * 64;
  __shared__ __align__(16) bf16 lds[4][16384];  // slot 32KB: A 16KB + B 16KB
  f32x4 acc[8][4];
#pragma unroll
  for (int a = 0; a < 8; a++)
#pragma unroll
    for (int n = 0; n < 4; n++) acc[a][n] = F32X4_ZERO;

  constexpr int K = 1024, nk = K / 32;
  int rin = lane >> 2;                              // row in 16-row chunk
  int sbc = ((lane & 3) ^ ((lane >> 3) & 3)) * 16;  // pre-swizzled src byte col
  auto stage = [&](int slot, int k0) {
#pragma unroll
    for (int j = 0; j < 4; j++) {
      int c = wv * 4 + j;                           // 0..31
      if (c < 16)
        gld16((const char*)A + ((size_t)(m0 + c * 16 + rin) * K + k0) * 2 + sbc,
              (char*)lds[slot] + c * 1024);
      else
        gld16((const char*)BT + ((size_t)(n0 + (c - 16) * 16 + rin) * K + k0) * 2 + sbc,
              (char*)lds[slot] + c * 1024);
    }
  };

  stage(0, 0); stage(1, 32); stage(2, 64);          // 12 loads in flight
#pragma unroll 1
  for (int t = 0; t < nk; t++) {
    if (t < nk - 2)       WAITB(8);   // stage(t) landed; t+1,t+2 stay in flight
    else if (t == nk - 2) WAITB(4);
    else                  WAITB(0);
    if (t + 3 < nk) stage((t + 3) & 3, (t + 3) * 32);
    const bf16* As = lds[t & 3];
    const bf16* Bs = lds[t & 3] + 8192;
    int c16 = lane >> 4;
    bf16x8 bfr[4];
#pragma unroll
    for (int nf = 0; nf < 4; nf++)
      bfr[nf] = frag_ld32(Bs, wcol + nf * 16 + (lane & 15), c16);
    __builtin_amdgcn_s_setprio(1);
#pragma unroll
    for (int mf = 0; mf < 8; mf++) {
      bf16x8 af = frag_ld32(As, wrow + mf * 16 + (lane & 15), c16);
#pragma unroll
      for (int nf = 0; nf < 4; nf++)
        acc[mf][nf] = mfma16(af, bfr[nf], acc[mf][nf]);
    }
    __builtin_amdgcn_s_setprio(0);
  }
#pragma unroll
  for (int mf = 0; mf < 8; mf++)
#pragma unroll
    for (int nf = 0; nf < 4; nf++)
#pragma unroll
      for (int i = 0; i < 4; i++) {
        int row = m0 + wrow + mf * 16 + ((lane >> 4) << 2) + i;
        int col = n0 + wcol + nf * 16 + (lane & 15);
        outb[(size_t)row * N + col] = (bf16)gelu_f(acc[mf][nf][i] + bias[col]);
      }
}

// ---------------------------------------------------------------- 128^2 pipe
enum { EPI_WO = 0, EPI_GELU = 1, EPI_ACC0 = 2, EPI_ACC = 3, EPI_FINAL = 4 };

template <int EPI, int K>
__global__ __launch_bounds__(256) void pipe128(
    const bf16* __restrict__ A, const bf16* __restrict__ BT, const float* __restrict__ bias,
    int N,
    const float* __restrict__ resid, float* __restrict__ facc,
    bf16* __restrict__ outb, float* __restrict__ outf) {
  int tid = threadIdx.x, lane = tid & 63, wv = tid >> 6;
  int bid = blockIdx.x + (blockIdx.y << 3);
  int xcd = bid & 7, idx = bid >> 3;
  int m0 = (xcd * 4 + (idx >> 3)) * 128, n0 = (idx & 7) * 128;
  int wrow = (wv >> 1) * 64, wcol = (wv & 1) * 64;
  __shared__ __align__(16) bf16 lds[4][8192];  // slot 16KB: A 8KB + B 8KB
  f32x4 acc[4][4];
#pragma unroll
  for (int a = 0; a < 4; a++)
#pragma unroll
    for (int n = 0; n < 4; n++) acc[a][n] = F32X4_ZERO;

  constexpr int nk = K / 32;
  int rin = lane >> 2;
  int sbc = ((lane & 3) ^ ((lane >> 3) & 3)) * 16;
  auto stage = [&](int slot, int k0) {
#pragma unroll
    for (int j = 0; j < 4; j++) {
      int c = wv * 4 + j;                           // 0..15
      if (c < 8)
        gld16((const char*)A + ((size_t)(m0 + c * 16 + rin) * K + k0) * 2 + sbc,
              (char*)lds[slot] + c * 1024);
      else
        gld16((const char*)BT + ((size_t)(n0 + (c - 8) * 16 + rin) * K + k0) * 2 + sbc,
              (char*)lds[slot] + c * 1024);
    }
  };

  stage(0, 0); stage(1, 32); stage(2, 64);
#pragma unroll 1
  for (int t = 0; t < nk; t++) {
    if (t < nk - 2)       WAITB(8);
    else if (t == nk - 2) WAITB(4);
    else                  WAITB(0);
    if (t + 3 < nk) stage((t + 3) & 3, (t + 3) * 32);
    const bf16* As = lds[t & 3];
    const bf16* Bs = lds[t & 3] + 4096;
    int c16 = lane >> 4;
    bf16x8 af[4], bfr[4];
#pragma unroll
    for (int mf = 0; mf < 4; mf++)
      af[mf] = frag_ld32(As, wrow + mf * 16 + (lane & 15), c16);
#pragma unroll
    for (int nf = 0; nf < 4; nf++)
      bfr[nf] = frag_ld32(Bs, wcol + nf * 16 + (lane & 15), c16);
    __builtin_amdgcn_s_setprio(1);
#pragma unroll
    for (int mf = 0; mf < 4; mf++)
#pragma unroll
      for (int nf = 0; nf < 4; nf++)
        acc[mf][nf] = mfma16(af[mf], bfr[nf], acc[mf][nf]);
    __builtin_amdgcn_s_setprio(0);
  }
#pragma unroll
  for (int mf = 0; mf < 4; mf++)
#pragma unroll
    for (int nf = 0; nf < 4; nf++)
#pragma unroll
      for (int i = 0; i < 4; i++) {
        int row = m0 + wrow + mf * 16 + ((lane >> 4) << 2) + i;
        int col = n0 + wcol + nf * 16 + (lane & 15);
        size_t idx2 = (size_t)row * N + col;
        float v = acc[mf][nf][i];
        if constexpr (EPI == EPI_WO) {
          outf[idx2] = v + bias[col] + resid[idx2];
        } else if constexpr (EPI == EPI_GELU) {
          outb[idx2] = (bf16)gelu_f(v + bias[col]);
        } else if constexpr (EPI == EPI_ACC0) {
          facc[idx2] = v;
        } else if constexpr (EPI == EPI_ACC) {
          facc[idx2] += v;
        } else {
          outf[idx2] = facc[idx2] + v + bias[col] + resid[idx2];
        }
      }
}

// ---------------------------------------------------------------- QKV pipe
// x1[4096][1024] @ WT[1024][1024] + bias; q scaled 1/8; V transposed out.
__global__ __launch_bounds__(256) void qkv_pipe(
    const bf16* __restrict__ x1,
    const bf16* __restrict__ WqT, const bf16* __restrict__ WkT, const bf16* __restrict__ WvT,
    const float* __restrict__ bq, const float* __restrict__ bk, const float* __restrict__ bv,
    bf16* __restrict__ qo, bf16* __restrict__ ko, bf16* __restrict__ vto) {
  int tid = threadIdx.x, lane = tid & 63, wv = tid >> 6;
  int z = blockIdx.z;
  const bf16* BT; const float* bias;
  if (z == 0)      { BT = WqT; bias = bq; }
  else if (z == 1) { BT = WkT; bias = bk; }
  else             { BT = WvT; bias = bv; }
  int bid = blockIdx.x + (blockIdx.y << 3);
  int xcd = bid & 7, idx = bid >> 3;
  int m0 = (xcd * 4 + (idx >> 3)) * 128, n0 = (idx & 7) * 128;
  int wrow = (wv >> 1) * 64, wcol = (wv & 1) * 64;
  __shared__ __align__(16) bf16 lds[4][8192];
  f32x4 acc[4][4];
#pragma unroll
  for (int a = 0; a < 4; a++)
#pragma unroll
    for (int n = 0; n < 4; n++) acc[a][n] = F32X4_ZERO;

  constexpr int K = 1024, nk = K / 32;
  int rin = lane >> 2;
  int sbc = ((lane & 3) ^ ((lane >> 3) & 3)) * 16;
  auto stage = [&](int slot, int k0) {
#pragma unroll
    for (int j = 0; j < 4; j++) {
      int c = wv * 4 + j;
      if (c < 8)
        gld16((const char*)x1 + ((size_t)(m0 + c * 16 + rin) * K + k0) * 2 + sbc,
              (char*)lds[slot] + c * 1024);
      else
        gld16((const char*)BT + ((size_t)(n0 + (c - 8) * 16 + rin) * K + k0) * 2 + sbc,
              (char*)lds[slot] + c * 1024);
    }
  };

  stage(0, 0); stage(1, 32); stage(2, 64);
#pragma unroll 1
  for (int t = 0; t < nk; t++) {
    if (t < nk - 2)       WAITB(8);
    else if (t == nk - 2) WAITB(4);
    else                  WAITB(0);
    if (t + 3 < nk) stage((t + 3) & 3, (t + 3) * 32);
    const bf16* As = lds[t & 3];
    const bf16* Bs = lds[t & 3] + 4096;
    int c16 = lane >> 4;
    bf16x8 af[4], bfr[4];
#pragma unroll
    for (int mf = 0; mf < 4; mf++)
      af[mf] = frag_ld32(As, wrow + mf * 16 + (lane & 15), c16);
#pragma unroll
    for (int nf = 0; nf < 4; nf++)
      bfr[nf] = frag_ld32(Bs, wcol + nf * 16 + (lane & 15), c16);
    __builtin_amdgcn_s_setprio(1);
#pragma unroll
    for (int mf = 0; mf < 4; mf++)
#pragma unroll
      for (int nf = 0; nf < 4; nf++)
        acc[mf][nf] = mfma16(af[mf], bfr[nf], acc[mf][nf]);
    __builtin_amdgcn_s_setprio(0);
  }
#pragma unroll
  for (int mf = 0; mf < 4; mf++)
#pragma unroll
    for (int nf = 0; nf < 4; nf++)
#pragma unroll
      for (int i = 0; i < 4; i++) {
        int row  = m0 + wrow + mf * 16 + ((lane >> 4) << 2) + i;
        int ncol = n0 + wcol + nf * 16 + (lane & 15);
        int bb = row >> 10, s = row & 1023, head = ncol >> 6, d = ncol & 63;
        size_t bh = (size_t)bb * 16 + head;
        float v = acc[mf][nf][i] + bias[ncol];
        if (z == 0)      qo[(bh * 1024 + s) * 64 + d] = (bf16)(v * 0.125f);
        else if (z == 1) ko[(bh * 1024 + s) * 64 + d] = (bf16)v;
        else             vto[(bh * 64 + d) * 1024 + s] = (bf16)v;
      }
}

// ---------------------------------------------------------------- attention
// GEMM-style pipelined flash attention (r9 structure, unchanged; BK=64 swizzle).
__global__ __launch_bounds__(512) void attn_flash(
    const bf16* __restrict__ qb, const bf16* __restrict__ kb, const bf16* __restrict__ vtb,
    const int* __restrict__ mask, bf16* __restrict__ attnC) {
  int tid = threadIdx.x, lane = tid & 63, wv = tid >> 6;
  int wgid = blockIdx.x;
  int nid  = (wgid & 7) * 64 + (wgid >> 3);
  int qblk = nid & 7, h = (nid >> 3) & 15, b = nid >> 7;
  int qrow0 = qblk * 128 + wv * 16;

  __shared__ float smask[1024];
  __shared__ __align__(16) bf16 kt[2][64 * 64];
  __shared__ __align__(16) bf16 vt[2][64 * 64];
  __shared__ __align__(16) bf16 pb[8][16][72];
  for (int i = tid; i < 1024; i += 512) smask[i] = mask[b * 1024 + i] ? 0.f : -1e9f;

  size_t bh = (size_t)b * 16 + h;
  const bf16* qp = qb + (bh * 1024 + qrow0) * 64;
  bf16x8 qa[2];
#pragma unroll
  for (int kc = 0; kc < 2; kc++)
    qa[kc] = *(const bf16x8*)(qp + (lane & 15) * 64 + kc * 32 + (lane >> 4) * 8);

  const bf16* kp = kb + bh * 1024 * 64;
  const bf16* vp = vtb + bh * 64 * 1024;
  bf16* myp = &pb[wv][0][0];

  bf16x8 vone;
#pragma unroll
  for (int j = 0; j < 8; j++) vone[j] = (bf16)1.0f;

  f32x4 ssum = F32X4_ZERO;
  f32x4 oacc[4];
#pragma unroll
  for (int i = 0; i < 4; i++) oacc[i] = F32X4_ZERO;

  int srl = lane >> 3;
  int sbc = ((lane & 7) ^ srl) * 16;
  auto stage = [&](int buf, int t2) {
    int key0n = t2 * 64;
#pragma unroll
    for (int j = 0; j < 2; j++) {
      int c = wv * 2 + j;
      if (c < 8) {
        int row = c * 8 + srl;
        gld16((const char*)kp + ((size_t)(key0n + row) * 64) * 2 + sbc,
              (char*)kt[buf] + c * 1024);
      } else {
        int row = (c - 8) * 8 + srl;
        gld16((const char*)vp + ((size_t)row * 1024 + key0n) * 2 + sbc,
              (char*)vt[buf] + (c - 8) * 1024);
      }
    }
  };

  stage(0, 0);
  __syncthreads();

  for (int t = 0; t < 16; t++) {
    int cur = t & 1;
    if (t < 15) stage(cur ^ 1, t + 1);
    const bf16* kcur = kt[cur];
    const bf16* vcur = vt[cur];
    int key0 = t * 64;
    f32x4 st[4];
    __builtin_amdgcn_s_setprio(1);
#pragma unroll
    for (int nt = 0; nt < 4; nt++) {
      st[nt] = F32X4_ZERO;
#pragma unroll
      for (int kc = 0; kc < 2; kc++) {
        bf16x8 kf = frag_ld(kcur, nt * 16 + (lane & 15), kc * 4 + (lane >> 4));
        st[nt] = mfma16(qa[kc], kf, st[nt]);
      }
    }
    __builtin_amdgcn_s_setprio(0);
#pragma unroll
    for (int nt = 0; nt < 4; nt++) {
      float ms = smask[key0 + nt * 16 + (lane & 15)] - 8.0f;
#pragma unroll
      for (int i = 0; i < 4; i++) st[nt][i] = __expf(st[nt][i] + ms);
    }
#pragma unroll
    for (int nt = 0; nt < 4; nt++)
#pragma unroll
      for (int i = 0; i < 4; i++)
        myp[((lane >> 4) * 4 + i) * 72 + nt * 16 + (lane & 15)] = (bf16)st[nt][i];
    __builtin_amdgcn_s_setprio(1);
#pragma unroll
    for (int kc = 0; kc < 2; kc++) {
      bf16x8 pa = *(const bf16x8*)(myp + (lane & 15) * 72 + kc * 32 + (lane >> 4) * 8);
      ssum = mfma16(pa, vone, ssum);
#pragma unroll
      for (int dn = 0; dn < 4; dn++) {
        bf16x8 vf = frag_ld(vcur, dn * 16 + (lane & 15), kc * 4 + (lane >> 4));
        oacc[dn] = mfma16(pa, vf, oacc[dn]);
      }
    }
    __builtin_amdgcn_s_setprio(0);
    __syncthreads();
  }
#pragma unroll
  for (int i = 0; i < 4; i++) {
    float inv = 1.0f / ssum[i];
    int row = qrow0 + ((lane >> 4) << 2) + i;
#pragma unroll
    for (int dn = 0; dn < 4; dn++)
      attnC[(size_t)(b * 1024 + row) * 1024 + h * 64 + dn * 16 + (lane & 15)] =
          (bf16)(oacc[dn][i] * inv);
  }
}

// ---------------------------------------------------------------- old 128^2 (chunked path only)
template <int EPI, int K>
__global__ __launch_bounds__(256) void gemm_bt(
    const bf16* __restrict__ A, const bf16* __restrict__ BT, const float* __restrict__ bias,
    int N,
    const float* __restrict__ resid, float* __restrict__ facc,
    bf16* __restrict__ outb, float* __restrict__ outf) {
  int tid = threadIdx.x, lane = tid & 63, wv = tid >> 6;
  int m0 = blockIdx.y * 128, n0 = blockIdx.x * 128;
  int wrow = (wv >> 1) * 64, wcol = (wv & 1) * 64;
  __shared__ __align__(16) bf16 lA[2][128 * 64];
  __shared__ __align__(16) bf16 lB[2][128 * 64];
  f32x4 acc[4][4];
#pragma unroll
  for (int a = 0; a < 4; a++)
#pragma unroll
    for (int n = 0; n < 4; n++) acc[a][n] = F32X4_ZERO;

  int cbs = ((lane & 7) ^ (lane >> 3)) * 16;
  auto stage = [&](int buf, int k0) {
#pragma unroll
    for (int s = 0; s < 4; s++) {
      int c = s * 4 + wv;
      int row = c * 8 + (lane >> 3);
      gld16((const char*)A  + ((size_t)(m0 + row) * K + k0) * 2 + cbs,
            (char*)lA[buf] + c * 1024);
      gld16((const char*)BT + ((size_t)(n0 + row) * K + k0) * 2 + cbs,
            (char*)lB[buf] + c * 1024);
    }
  };

  constexpr int nk = K >> 6;
  stage(0, 0);
  __syncthreads();
#pragma unroll 1
  for (int t = 0; t < nk; t++) {
    int cur = t & 1;
    if (t + 1 < nk) stage(cur ^ 1, (t + 1) * 64);
#pragma unroll
    for (int kc = 0; kc < 2; kc++) {
      int c16 = kc * 4 + (lane >> 4);
      bf16x8 af[4], bfr[4];
#pragma unroll
      for (int mf = 0; mf < 4; mf++)
        af[mf] = frag_ld(lA[cur], wrow + mf * 16 + (lane & 15), c16);
#pragma unroll
      for (int nf = 0; nf < 4; nf++)
        bfr[nf] = frag_ld(lB[cur], wcol + nf * 16 + (lane & 15), c16);
#pragma unroll
      for (int mf = 0; mf < 4; mf++)
#pragma unroll
        for (int nf = 0; nf < 4; nf++)
          acc[mf][nf] = mfma16(af[mf], bfr[nf], acc[mf][nf]);
    }
    __syncthreads();
  }
#pragma unroll
  for (int mf = 0; mf < 4; mf++)
#pragma unroll
    for (int nf = 0; nf < 4; nf++)
#pragma unroll
      for (int i = 0; i < 4; i++) {
        int row = m0 + wrow + mf * 16 + ((lane >> 4) << 2) + i;
        int col = n0 + wcol + nf * 16 + (lane & 15);
        size_t idx2 = (size_t)row * N + col;
        float v = acc[mf][nf][i];
        if constexpr (EPI == EPI_WO) {
          outf[idx2] = v + bias[col] + resid[idx2];
        } else if constexpr (EPI == EPI_GELU) {
          outb[idx2] = (bf16)gelu_f(v + bias[col]);
        } else if constexpr (EPI == EPI_ACC0) {
          facc[idx2] = v;
        } else if constexpr (EPI == EPI_ACC) {
          facc[idx2] += v;
        } else {
          outf[idx2] = facc[idx2] + v + bias[col] + resid[idx2];
        }
      }
}

// ---------------------------------------------------------------- launch
extern "C" void kernel_launch(void* const* d_in, const int* in_sizes, int n_in,
                              void* d_out, int out_size, void* d_ws, size_t ws_size,
                              hipStream_t stream) {
  const float* hidden = (const float*)d_in[0];
  const int*   mask   = (const int*)d_in[1];
  const float* Wq = (const float*)d_in[2];
  const float* bq = (const float*)d_in[3];
  const float* Wk = (const float*)d_in[4];
  const float* bk = (const float*)d_in[5];
  const float* Wv = (const float*)d_in[6];
  const float* bv = (const float*)d_in[7];
  const float* Wo = (const float*)d_in[8];
  const float* bo = (const float*)d_in[9];
  const float* ln1g = (const float*)d_in[10];
  const float* ln1b = (const float*)d_in[11];
  const float* ln2g = (const float*)d_in[12];
  const float* ln2b = (const float*)d_in[13];
  const float* W1 = (const float*)d_in[14];
  const float* b1 = (const float*)d_in[15];
  const float* W2 = (const float*)d_in[16];
  const float* b2 = (const float*)d_in[17];
  float* out = (float*)d_out;

  char* ws = (char*)d_ws;
  const size_t MB = 1ull << 20;
  dim3 tb(32, 8);
  const size_t HB = 64 * 1024;

  if (ws_size >= 96 * MB) {
    // ---------------- simple path (88 MB) ----------------
    bf16* x1    = (bf16*)(ws + 0 * MB);
    bf16* attnC = x1;
    bf16* x2    = x1;
    bf16* qbuf  = (bf16*)(ws + 8 * MB);
    bf16* W1T   = qbuf;
    bf16* kbuf  = (bf16*)(ws + 16 * MB);
    bf16* W2T   = kbuf;
    bf16* vtbuf = (bf16*)(ws + 24 * MB);
    float* hbuf = (float*)(ws + 32 * MB);
    bf16* WqT   = (bf16*)(ws + 48 * MB);
    bf16* WkT   = (bf16*)(ws + 50 * MB);
    bf16* WvT   = (bf16*)(ws + 52 * MB);
    bf16* WoT   = (bf16*)(ws + 54 * MB);
    bf16* gbuf  = (bf16*)(ws + 56 * MB);

    transpose2<<<dim3(2, 32, 16), tb, 0, stream>>>(Wq, HB, 64, WqT, HB, 1024);
    transpose2<<<dim3(2, 32, 16), tb, 0, stream>>>(Wk, HB, 64, WkT, HB, 1024);
    transpose2<<<dim3(2, 32, 16), tb, 0, stream>>>(Wv, HB, 64, WvT, HB, 1024);
    transpose2<<<dim3(32, 32, 1), tb, 0, stream>>>(Wo, 0, 1024, WoT, 0, 1024);
    ln_rows<<<4096, 256, 0, stream>>>(hidden, ln1g, ln1b, x1);
    qkv_pipe<<<dim3(8, 32, 3), 256, 0, stream>>>(x1, WqT, WkT, WvT, bq, bk, bv,
                                                 qbuf, kbuf, vtbuf);
    attn_flash<<<512, 512, 0, stream>>>(qbuf, kbuf, vtbuf, mask, attnC);
    pipe128<EPI_WO, 1024><<<dim3(8, 32), 256, 0, stream>>>(attnC, WoT, bo, 1024,
                                                           hidden, nullptr, nullptr, hbuf);
    ln_rows<<<4096, 256, 0, stream>>>(hbuf, ln2g, ln2b, x2);
    transpose2<<<dim3(128, 32, 1), tb, 0, stream>>>(W1, 0, 4096, W1T, 0, 1024);
    transpose2<<<dim3(32, 128, 1), tb, 0, stream>>>(W2, 0, 1024, W2T, 0, 4096);
    pipe256_gelu<<<dim3(16, 16), 512, 0, stream>>>(x2, W1T, b1, 4096, gbuf);
    pipe128<EPI_WO, 4096><<<dim3(8, 32), 256, 0, stream>>>(gbuf, W2T, b2, 1024,
                                                           hbuf, nullptr, nullptr, out);
  } else {
    // ---------------- chunked path (56 MB, old engine) ----------------
    bf16* x1     = (bf16*)(ws + 0 * MB);
    bf16* attnC  = x1;
    bf16* x2     = x1;
    bf16* qbuf   = (bf16*)(ws + 8 * MB);
    bf16* W1Tc   = (bf16*)(ws + 8 * MB);
    bf16* W2Tc   = (bf16*)(ws + 10 * MB);
    bf16* gchunk = (bf16*)(ws + 12 * MB);
    bf16* kbuf   = (bf16*)(ws + 16 * MB);
    bf16* vtbuf  = (bf16*)(ws + 24 * MB);
    float* hbuf  = (float*)(ws + 16 * MB);
    bf16* WqT    = (bf16*)(ws + 32 * MB);
    bf16* WkT    = (bf16*)(ws + 34 * MB);
    bf16* WvT    = (bf16*)(ws + 36 * MB);
    bf16* WoT    = (bf16*)(ws + 38 * MB);
    float* outacc = (float*)(ws + 40 * MB);

    transpose2<<<dim3(2, 32, 16), tb, 0, stream>>>(Wq, HB, 64, WqT, HB, 1024);
    transpose2<<<dim3(2, 32, 16), tb, 0, stream>>>(Wk, HB, 64, WkT, HB, 1024);
    transpose2<<<dim3(2, 32, 16), tb, 0, stream>>>(Wv, HB, 64, WvT, HB, 1024);
    transpose2<<<dim3(32, 32, 1), tb, 0, stream>>>(Wo, 0, 1024, WoT, 0, 1024);
    ln_rows<<<4096, 256, 0, stream>>>(hidden, ln1g, ln1b, x1);
    qkv_pipe<<<dim3(8, 32, 3), 256, 0, stream>>>(x1, WqT, WkT, WvT, bq, bk, bv,
                                                 qbuf, kbuf, vtbuf);
    attn_flash<<<512, 512, 0, stream>>>(qbuf, kbuf, vtbuf, mask, attnC);
    pipe128<EPI_WO, 1024><<<dim3(8, 32), 256, 0, stream>>>(attnC, WoT, bo, 1024,
                                                           hidden, nullptr, nullptr, hbuf);
    ln_rows<<<4096, 256, 0, stream>>>(hbuf, ln2g, ln2b, x2);

    for (int c = 0; c < 8; c++) {
      transpose2<<<dim3(16, 32, 1), tb, 0, stream>>>(W1 + c * 512, 0, 4096,
                                                     W1Tc, 0, 1024);
      transpose2<<<dim3(32, 16, 1), tb, 0, stream>>>(W2 + (size_t)c * 512 * 1024, 0, 1024,
                                                     W2Tc, 0, 512);
      gemm_bt<EPI_GELU, 1024><<<dim3(4, 32), 256, 0, stream>>>(x2, W1Tc, b1 + c * 512, 512,
                                                               nullptr, nullptr, gchunk, nullptr);
      if (c == 0)
        gemm_bt<EPI_ACC0, 512><<<dim3(8, 32), 256, 0, stream>>>(gchunk, W2Tc, b2, 1024,
                                                                nullptr, outacc, nullptr, nullptr);
      else if (c < 7)
        gemm_bt<EPI_ACC, 512><<<dim3(8, 32), 256, 0, stream>>>(gchunk, W2Tc, b2, 1024,
                                                               nullptr, outacc, nullptr, nullptr);
      else
        gemm_bt<EPI_FINAL, 512><<<dim3(8, 32), 256, 0, stream>>>(gchunk, W2Tc, b2, 1024,
                                                                 hbuf, outacc, nullptr, out);
    }
  }

  (void)in_sizes; (void)n_in; (void)out_size;
}

// Round 15
// 231.404 us; speedup vs baseline: 1.3221x; 1.1380x over previous
//
#include <hip/hip_runtime.h>

typedef __bf16 bf16;
typedef __bf16 bf16x4 __attribute__((ext_vector_type(4)));
typedef __bf16 bf16x8 __attribute__((ext_vector_type(8)));
typedef float  f32x4  __attribute__((ext_vector_type(4)));

#define F32X4_ZERO ((f32x4){0.f, 0.f, 0.f, 0.f})

__device__ __forceinline__ f32x4 mfma16(bf16x8 a, bf16x8 b, f32x4 c) {
  return __builtin_amdgcn_mfma_f32_16x16x32_bf16(a, b, c, 0, 0, 0);
}

__device__ __forceinline__ void gld16(const void* g, void* l) {
  __builtin_amdgcn_global_load_lds((const __attribute__((address_space(1))) void*)g,
                                   (__attribute__((address_space(3))) void*)l, 16, 0, 0);
}

__device__ __forceinline__ float gelu_f(float u) {
  return 0.5f * u * (1.0f + erff(u * 0.70710678118654752f));
}

// ---- BK=64 tile helpers (attention + chunked-path engine) ----
__device__ __forceinline__ bf16x8 frag_ld(const bf16* base, int row, int c16) {
  return *(const bf16x8*)((const char*)base + row * 128 + (((c16) ^ (row & 7)) << 4));
}

// ---- BK=32 tile helpers (counted-vmcnt pipeline engine) ----
// row = 64B; chunk = 1KB = 16 rows. phys slot = c16 ^ ((row>>1)&3)  (2-way free).
__device__ __forceinline__ bf16x8 frag_ld32(const bf16* base, int row, int c16) {
  return *(const bf16x8*)((const char*)base + row * 64 + ((c16 ^ ((row >> 1) & 3)) << 4));
}
#define WAITB(N) asm volatile("s_waitcnt vmcnt(" #N ")\ns_barrier" ::: "memory")

// ---------------------------------------------------------------- transpose
__global__ void transpose2(const float* __restrict__ src, size_t sBatch, int sStride,
                           bf16* __restrict__ dst, size_t dBatch, int dStride) {
  __shared__ bf16 t[32][33];
  src += (size_t)blockIdx.z * sBatch;
  dst += (size_t)blockIdx.z * dBatch;
  int c0 = blockIdx.x * 32, r0 = blockIdx.y * 32;
#pragma unroll
  for (int i = 0; i < 4; i++) {
    int r = threadIdx.y + i * 8;
    t[r][threadIdx.x] = (bf16)src[(size_t)(r0 + r) * sStride + c0 + threadIdx.x];
  }
  __syncthreads();
#pragma unroll
  for (int i = 0; i < 4; i++) {
    int c = threadIdx.y + i * 8;
    dst[(size_t)(c0 + c) * dStride + r0 + threadIdx.x] = t[threadIdx.x][c];
  }
}

// ---------------------------------------------------------------- layernorm
__global__ __launch_bounds__(256) void ln_rows(const float* __restrict__ in,
                                               const float* __restrict__ gam,
                                               const float* __restrict__ bet,
                                               bf16* __restrict__ out) {
  int row = blockIdx.x, tid = threadIdx.x;
  f32x4 x = *(const f32x4*)(in + (size_t)row * 1024 + tid * 4);
  float s = 0.f, q = 0.f;
#pragma unroll
  for (int j = 0; j < 4; j++) { s += x[j]; q += x[j] * x[j]; }
#pragma unroll
  for (int o = 1; o < 64; o <<= 1) {
    s += __shfl_xor(s, o, 64);
    q += __shfl_xor(q, o, 64);
  }
  __shared__ float red[8];
  if ((tid & 63) == 0) { red[(tid >> 6) * 2] = s; red[(tid >> 6) * 2 + 1] = q; }
  __syncthreads();
  s = red[0] + red[2] + red[4] + red[6];
  q = red[1] + red[3] + red[5] + red[7];
  float mean = s * (1.f / 1024.f);
  float var  = q * (1.f / 1024.f) - mean * mean;
  float inv  = rsqrtf(var + 1e-6f);
  bf16x4 o;
#pragma unroll
  for (int j = 0; j < 4; j++) {
    int c = tid * 4 + j;
    o[j] = (bf16)((x[j] - mean) * inv * gam[c] + bet[c]);
  }
  *(bf16x4*)(out + (size_t)row * 1024 + tid * 4) = o;
}

// ============================================================ pipe engine
// 128x128 tile, BK=32, 3-slot LDS (48KB -> 3 blocks/CU), depth-2 prefetch,
// counted vmcnt(4/0) + raw barrier, conflict-free swizzle, no setprio.
enum { EPI_WO = 0, EPI_GELU = 1, EPI_ACC0 = 2, EPI_ACC = 3, EPI_FINAL = 4 };

template <int EPI, int K, int NTL>   // NTL: log2(#n-tiles per XCD group)
__global__ __launch_bounds__(256) void pipe128(
    const bf16* __restrict__ A, const bf16* __restrict__ BT, const float* __restrict__ bias,
    int N,
    const float* __restrict__ resid, float* __restrict__ facc,
    bf16* __restrict__ outb, float* __restrict__ outf) {
  int tid = threadIdx.x, lane = tid & 63, wv = tid >> 6;
  int bid = blockIdx.x + (blockIdx.y << 3);
  int xcd = bid & 7, idx = bid >> 3;
  int m0 = (xcd * 4 + (idx >> NTL)) * 128;
  int n0 = (idx & ((1 << NTL) - 1)) * 128;
  int wrow = (wv >> 1) * 64, wcol = (wv & 1) * 64;
  __shared__ __align__(16) bf16 lds[3][8192];  // slot 16KB: A 8KB + B 8KB
  f32x4 acc[4][4];
#pragma unroll
  for (int a = 0; a < 4; a++)
#pragma unroll
    for (int n = 0; n < 4; n++) acc[a][n] = F32X4_ZERO;

  constexpr int nk = K / 32;
  int rin = lane >> 2;
  int sbc = ((lane & 3) ^ ((lane >> 3) & 3)) * 16;
  auto stage = [&](int slot, int k0) {
#pragma unroll
    for (int j = 0; j < 4; j++) {
      int c = wv * 4 + j;                           // 0..15
      if (c < 8)
        gld16((const char*)A + ((size_t)(m0 + c * 16 + rin) * K + k0) * 2 + sbc,
              (char*)lds[slot] + c * 1024);
      else
        gld16((const char*)BT + ((size_t)(n0 + (c - 8) * 16 + rin) * K + k0) * 2 + sbc,
              (char*)lds[slot] + c * 1024);
    }
  };

  stage(0, 0); stage(1, 32);
#pragma unroll 1
  for (int t = 0; t < nk; t++) {
    if (t < nk - 1) WAITB(4);   // stage(t) landed; stage(t+1) stays in flight
    else            WAITB(0);
    if (t + 2 < nk) stage((t + 2) % 3, (t + 2) * 32);
    const bf16* As = lds[t % 3];
    const bf16* Bs = lds[t % 3] + 4096;
    int c16 = lane >> 4;
    bf16x8 af[4], bfr[4];
#pragma unroll
    for (int mf = 0; mf < 4; mf++)
      af[mf] = frag_ld32(As, wrow + mf * 16 + (lane & 15), c16);
#pragma unroll
    for (int nf = 0; nf < 4; nf++)
      bfr[nf] = frag_ld32(Bs, wcol + nf * 16 + (lane & 15), c16);
#pragma unroll
    for (int mf = 0; mf < 4; mf++)
#pragma unroll
      for (int nf = 0; nf < 4; nf++)
        acc[mf][nf] = mfma16(af[mf], bfr[nf], acc[mf][nf]);
  }
#pragma unroll
  for (int mf = 0; mf < 4; mf++)
#pragma unroll
    for (int nf = 0; nf < 4; nf++)
#pragma unroll
      for (int i = 0; i < 4; i++) {
        int row = m0 + wrow + mf * 16 + ((lane >> 4) << 2) + i;
        int col = n0 + wcol + nf * 16 + (lane & 15);
        size_t idx2 = (size_t)row * N + col;
        float v = acc[mf][nf][i];
        if constexpr (EPI == EPI_WO) {
          outf[idx2] = v + bias[col] + resid[idx2];
        } else if constexpr (EPI == EPI_GELU) {
          outb[idx2] = (bf16)gelu_f(v + bias[col]);
        } else if constexpr (EPI == EPI_ACC0) {
          facc[idx2] = v;
        } else if constexpr (EPI == EPI_ACC) {
          facc[idx2] += v;
        } else {
          outf[idx2] = facc[idx2] + v + bias[col] + resid[idx2];
        }
      }
}

// ---------------------------------------------------------------- QKV pipe
// x1[4096][1024] @ WT[1024][1024] + bias; q scaled 1/8; V transposed out.
// Same 3-slot engine.
__global__ __launch_bounds__(256) void qkv_pipe(
    const bf16* __restrict__ x1,
    const bf16* __restrict__ WqT, const bf16* __restrict__ WkT, const bf16* __restrict__ WvT,
    const float* __restrict__ bq, const float* __restrict__ bk, const float* __restrict__ bv,
    bf16* __restrict__ qo, bf16* __restrict__ ko, bf16* __restrict__ vto) {
  int tid = threadIdx.x, lane = tid & 63, wv = tid >> 6;
  int z = blockIdx.z;
  const bf16* BT; const float* bias;
  if (z == 0)      { BT = WqT; bias = bq; }
  else if (z == 1) { BT = WkT; bias = bk; }
  else             { BT = WvT; bias = bv; }
  int bid = blockIdx.x + (blockIdx.y << 3);
  int xcd = bid & 7, idx = bid >> 3;
  int m0 = (xcd * 4 + (idx >> 3)) * 128, n0 = (idx & 7) * 128;
  int wrow = (wv >> 1) * 64, wcol = (wv & 1) * 64;
  __shared__ __align__(16) bf16 lds[3][8192];
  f32x4 acc[4][4];
#pragma unroll
  for (int a = 0; a < 4; a++)
#pragma unroll
    for (int n = 0; n < 4; n++) acc[a][n] = F32X4_ZERO;

  constexpr int K = 1024, nk = K / 32;
  int rin = lane >> 2;
  int sbc = ((lane & 3) ^ ((lane >> 3) & 3)) * 16;
  auto stage = [&](int slot, int k0) {
#pragma unroll
    for (int j = 0; j < 4; j++) {
      int c = wv * 4 + j;
      if (c < 8)
        gld16((const char*)x1 + ((size_t)(m0 + c * 16 + rin) * K + k0) * 2 + sbc,
              (char*)lds[slot] + c * 1024);
      else
        gld16((const char*)BT + ((size_t)(n0 + (c - 8) * 16 + rin) * K + k0) * 2 + sbc,
              (char*)lds[slot] + c * 1024);
    }
  };

  stage(0, 0); stage(1, 32);
#pragma unroll 1
  for (int t = 0; t < nk; t++) {
    if (t < nk - 1) WAITB(4);
    else            WAITB(0);
    if (t + 2 < nk) stage((t + 2) % 3, (t + 2) * 32);
    const bf16* As = lds[t % 3];
    const bf16* Bs = lds[t % 3] + 4096;
    int c16 = lane >> 4;
    bf16x8 af[4], bfr[4];
#pragma unroll
    for (int mf = 0; mf < 4; mf++)
      af[mf] = frag_ld32(As, wrow + mf * 16 + (lane & 15), c16);
#pragma unroll
    for (int nf = 0; nf < 4; nf++)
      bfr[nf] = frag_ld32(Bs, wcol + nf * 16 + (lane & 15), c16);
#pragma unroll
    for (int mf = 0; mf < 4; mf++)
#pragma unroll
      for (int nf = 0; nf < 4; nf++)
        acc[mf][nf] = mfma16(af[mf], bfr[nf], acc[mf][nf]);
  }
#pragma unroll
  for (int mf = 0; mf < 4; mf++)
#pragma unroll
    for (int nf = 0; nf < 4; nf++)
#pragma unroll
      for (int i = 0; i < 4; i++) {
        int row  = m0 + wrow + mf * 16 + ((lane >> 4) << 2) + i;
        int ncol = n0 + wcol + nf * 16 + (lane & 15);
        int bb = row >> 10, s = row & 1023, head = ncol >> 6, d = ncol & 63;
        size_t bh = (size_t)bb * 16 + head;
        float v = acc[mf][nf][i] + bias[ncol];
        if (z == 0)      qo[(bh * 1024 + s) * 64 + d] = (bf16)(v * 0.125f);
        else if (z == 1) ko[(bh * 1024 + s) * 64 + d] = (bf16)v;
        else             vto[(bh * 64 + d) * 1024 + s] = (bf16)v;
      }
}

// ---------------------------------------------------------------- attention
// GEMM-style pipelined flash attention (r9 structure, unchanged).
__global__ __launch_bounds__(512) void attn_flash(
    const bf16* __restrict__ qb, const bf16* __restrict__ kb, const bf16* __restrict__ vtb,
    const int* __restrict__ mask, bf16* __restrict__ attnC) {
  int tid = threadIdx.x, lane = tid & 63, wv = tid >> 6;
  int wgid = blockIdx.x;
  int nid  = (wgid & 7) * 64 + (wgid >> 3);
  int qblk = nid & 7, h = (nid >> 3) & 15, b = nid >> 7;
  int qrow0 = qblk * 128 + wv * 16;

  __shared__ float smask[1024];
  __shared__ __align__(16) bf16 kt[2][64 * 64];
  __shared__ __align__(16) bf16 vt[2][64 * 64];
  __shared__ __align__(16) bf16 pb[8][16][72];
  for (int i = tid; i < 1024; i += 512) smask[i] = mask[b * 1024 + i] ? 0.f : -1e9f;

  size_t bh = (size_t)b * 16 + h;
  const bf16* qp = qb + (bh * 1024 + qrow0) * 64;
  bf16x8 qa[2];
#pragma unroll
  for (int kc = 0; kc < 2; kc++)
    qa[kc] = *(const bf16x8*)(qp + (lane & 15) * 64 + kc * 32 + (lane >> 4) * 8);

  const bf16* kp = kb + bh * 1024 * 64;
  const bf16* vp = vtb + bh * 64 * 1024;
  bf16* myp = &pb[wv][0][0];

  bf16x8 vone;
#pragma unroll
  for (int j = 0; j < 8; j++) vone[j] = (bf16)1.0f;

  f32x4 ssum = F32X4_ZERO;
  f32x4 oacc[4];
#pragma unroll
  for (int i = 0; i < 4; i++) oacc[i] = F32X4_ZERO;

  int srl = lane >> 3;
  int sbc = ((lane & 7) ^ srl) * 16;
  auto stage = [&](int buf, int t2) {
    int key0n = t2 * 64;
#pragma unroll
    for (int j = 0; j < 2; j++) {
      int c = wv * 2 + j;
      if (c < 8) {
        int row = c * 8 + srl;
        gld16((const char*)kp + ((size_t)(key0n + row) * 64) * 2 + sbc,
              (char*)kt[buf] + c * 1024);
      } else {
        int row = (c - 8) * 8 + srl;
        gld16((const char*)vp + ((size_t)row * 1024 + key0n) * 2 + sbc,
              (char*)vt[buf] + (c - 8) * 1024);
      }
    }
  };

  stage(0, 0);
  __syncthreads();

  for (int t = 0; t < 16; t++) {
    int cur = t & 1;
    if (t < 15) stage(cur ^ 1, t + 1);
    const bf16* kcur = kt[cur];
    const bf16* vcur = vt[cur];
    int key0 = t * 64;
    f32x4 st[4];
    __builtin_amdgcn_s_setprio(1);
#pragma unroll
    for (int nt = 0; nt < 4; nt++) {
      st[nt] = F32X4_ZERO;
#pragma unroll
      for (int kc = 0; kc < 2; kc++) {
        bf16x8 kf = frag_ld(kcur, nt * 16 + (lane & 15), kc * 4 + (lane >> 4));
        st[nt] = mfma16(qa[kc], kf, st[nt]);
      }
    }
    __builtin_amdgcn_s_setprio(0);
#pragma unroll
    for (int nt = 0; nt < 4; nt++) {
      float ms = smask[key0 + nt * 16 + (lane & 15)] - 8.0f;
#pragma unroll
      for (int i = 0; i < 4; i++) st[nt][i] = __expf(st[nt][i] + ms);
    }
#pragma unroll
    for (int nt = 0; nt < 4; nt++)
#pragma unroll
      for (int i = 0; i < 4; i++)
        myp[((lane >> 4) * 4 + i) * 72 + nt * 16 + (lane & 15)] = (bf16)st[nt][i];
    __builtin_amdgcn_s_setprio(1);
#pragma unroll
    for (int kc = 0; kc < 2; kc++) {
      bf16x8 pa = *(const bf16x8*)(myp + (lane & 15) * 72 + kc * 32 + (lane >> 4) * 8);
      ssum = mfma16(pa, vone, ssum);
#pragma unroll
      for (int dn = 0; dn < 4; dn++) {
        bf16x8 vf = frag_ld(vcur, dn * 16 + (lane & 15), kc * 4 + (lane >> 4));
        oacc[dn] = mfma16(pa, vf, oacc[dn]);
      }
    }
    __builtin_amdgcn_s_setprio(0);
    __syncthreads();
  }
#pragma unroll
  for (int i = 0; i < 4; i++) {
    float inv = 1.0f / ssum[i];
    int row = qrow0 + ((lane >> 4) << 2) + i;
#pragma unroll
    for (int dn = 0; dn < 4; dn++)
      attnC[(size_t)(b * 1024 + row) * 1024 + h * 64 + dn * 16 + (lane & 15)] =
          (bf16)(oacc[dn][i] * inv);
  }
}

// ---------------------------------------------------------------- old 128^2 (chunked path only)
template <int EPI, int K>
__global__ __launch_bounds__(256) void gemm_bt(
    const bf16* __restrict__ A, const bf16* __restrict__ BT, const float* __restrict__ bias,
    int N,
    const float* __restrict__ resid, float* __restrict__ facc,
    bf16* __restrict__ outb, float* __restrict__ outf) {
  int tid = threadIdx.x, lane = tid & 63, wv = tid >> 6;
  int m0 = blockIdx.y * 128, n0 = blockIdx.x * 128;
  int wrow = (wv >> 1) * 64, wcol = (wv & 1) * 64;
  __shared__ __align__(16) bf16 lA[2][128 * 64];
  __shared__ __align__(16) bf16 lB[2][128 * 64];
  f32x4 acc[4][4];
#pragma unroll
  for (int a = 0; a < 4; a++)
#pragma unroll
    for (int n = 0; n < 4; n++) acc[a][n] = F32X4_ZERO;

  int cbs = ((lane & 7) ^ (lane >> 3)) * 16;
  auto stage = [&](int buf, int k0) {
#pragma unroll
    for (int s = 0; s < 4; s++) {
      int c = s * 4 + wv;
      int row = c * 8 + (lane >> 3);
      gld16((const char*)A  + ((size_t)(m0 + row) * K + k0) * 2 + cbs,
            (char*)lA[buf] + c * 1024);
      gld16((const char*)BT + ((size_t)(n0 + row) * K + k0) * 2 + cbs,
            (char*)lB[buf] + c * 1024);
    }
  };

  constexpr int nk = K >> 6;
  stage(0, 0);
  __syncthreads();
#pragma unroll 1
  for (int t = 0; t < nk; t++) {
    int cur = t & 1;
    if (t + 1 < nk) stage(cur ^ 1, (t + 1) * 64);
#pragma unroll
    for (int kc = 0; kc < 2; kc++) {
      int c16 = kc * 4 + (lane >> 4);
      bf16x8 af[4], bfr[4];
#pragma unroll
      for (int mf = 0; mf < 4; mf++)
        af[mf] = frag_ld(lA[cur], wrow + mf * 16 + (lane & 15), c16);
#pragma unroll
      for (int nf = 0; nf < 4; nf++)
        bfr[nf] = frag_ld(lB[cur], wcol + nf * 16 + (lane & 15), c16);
#pragma unroll
      for (int mf = 0; mf < 4; mf++)
#pragma unroll
        for (int nf = 0; nf < 4; nf++)
          acc[mf][nf] = mfma16(af[mf], bfr[nf], acc[mf][nf]);
    }
    __syncthreads();
  }
#pragma unroll
  for (int mf = 0; mf < 4; mf++)
#pragma unroll
    for (int nf = 0; nf < 4; nf++)
#pragma unroll
      for (int i = 0; i < 4; i++) {
        int row = m0 + wrow + mf * 16 + ((lane >> 4) << 2) + i;
        int col = n0 + wcol + nf * 16 + (lane & 15);
        size_t idx2 = (size_t)row * N + col;
        float v = acc[mf][nf][i];
        if constexpr (EPI == EPI_WO) {
          outf[idx2] = v + bias[col] + resid[idx2];
        } else if constexpr (EPI == EPI_GELU) {
          outb[idx2] = (bf16)gelu_f(v + bias[col]);
        } else if constexpr (EPI == EPI_ACC0) {
          facc[idx2] = v;
        } else if constexpr (EPI == EPI_ACC) {
          facc[idx2] += v;
        } else {
          outf[idx2] = facc[idx2] + v + bias[col] + resid[idx2];
        }
      }
}

// ---------------------------------------------------------------- launch
extern "C" void kernel_launch(void* const* d_in, const int* in_sizes, int n_in,
                              void* d_out, int out_size, void* d_ws, size_t ws_size,
                              hipStream_t stream) {
  const float* hidden = (const float*)d_in[0];
  const int*   mask   = (const int*)d_in[1];
  const float* Wq = (const float*)d_in[2];
  const float* bq = (const float*)d_in[3];
  const float* Wk = (const float*)d_in[4];
  const float* bk = (const float*)d_in[5];
  const float* Wv = (const float*)d_in[6];
  const float* bv = (const float*)d_in[7];
  const float* Wo = (const float*)d_in[8];
  const float* bo = (const float*)d_in[9];
  const float* ln1g = (const float*)d_in[10];
  const float* ln1b = (const float*)d_in[11];
  const float* ln2g = (const float*)d_in[12];
  const float* ln2b = (const float*)d_in[13];
  const float* W1 = (const float*)d_in[14];
  const float* b1 = (const float*)d_in[15];
  const float* W2 = (const float*)d_in[16];
  const float* b2 = (const float*)d_in[17];
  float* out = (float*)d_out;

  char* ws = (char*)d_ws;
  const size_t MB = 1ull << 20;
  dim3 tb(32, 8);
  const size_t HB = 64 * 1024;

  if (ws_size >= 96 * MB) {
    // ---------------- simple path (88 MB) ----------------
    bf16* x1    = (bf16*)(ws + 0 * MB);
    bf16* attnC = x1;
    bf16* x2    = x1;
    bf16* qbuf  = (bf16*)(ws + 8 * MB);
    bf16* W1T   = qbuf;
    bf16* kbuf  = (bf16*)(ws + 16 * MB);
    bf16* W2T   = kbuf;
    bf16* vtbuf = (bf16*)(ws + 24 * MB);
    float* hbuf = (float*)(ws + 32 * MB);
    bf16* WqT   = (bf16*)(ws + 48 * MB);
    bf16* WkT   = (bf16*)(ws + 50 * MB);
    bf16* WvT   = (bf16*)(ws + 52 * MB);
    bf16* WoT   = (bf16*)(ws + 54 * MB);
    bf16* gbuf  = (bf16*)(ws + 56 * MB);

    transpose2<<<dim3(2, 32, 16), tb, 0, stream>>>(Wq, HB, 64, WqT, HB, 1024);
    transpose2<<<dim3(2, 32, 16), tb, 0, stream>>>(Wk, HB, 64, WkT, HB, 1024);
    transpose2<<<dim3(2, 32, 16), tb, 0, stream>>>(Wv, HB, 64, WvT, HB, 1024);
    transpose2<<<dim3(32, 32, 1), tb, 0, stream>>>(Wo, 0, 1024, WoT, 0, 1024);
    ln_rows<<<4096, 256, 0, stream>>>(hidden, ln1g, ln1b, x1);
    qkv_pipe<<<dim3(8, 32, 3), 256, 0, stream>>>(x1, WqT, WkT, WvT, bq, bk, bv,
                                                 qbuf, kbuf, vtbuf);
    attn_flash<<<512, 512, 0, stream>>>(qbuf, kbuf, vtbuf, mask, attnC);
    pipe128<EPI_WO, 1024, 3><<<dim3(8, 32), 256, 0, stream>>>(attnC, WoT, bo, 1024,
                                                              hidden, nullptr, nullptr, hbuf);
    ln_rows<<<4096, 256, 0, stream>>>(hbuf, ln2g, ln2b, x2);
    transpose2<<<dim3(128, 32, 1), tb, 0, stream>>>(W1, 0, 4096, W1T, 0, 1024);
    transpose2<<<dim3(32, 128, 1), tb, 0, stream>>>(W2, 0, 1024, W2T, 0, 4096);
    pipe128<EPI_GELU, 1024, 5><<<dim3(8, 128), 256, 0, stream>>>(x2, W1T, b1, 4096,
                                                                 nullptr, nullptr, gbuf, nullptr);
    pipe128<EPI_WO, 4096, 3><<<dim3(8, 32), 256, 0, stream>>>(gbuf, W2T, b2, 1024,
                                                              hbuf, nullptr, nullptr, out);
  } else {
    // ---------------- chunked path (56 MB, old engine) ----------------
    bf16* x1     = (bf16*)(ws + 0 * MB);
    bf16* attnC  = x1;
    bf16* x2     = x1;
    bf16* qbuf   = (bf16*)(ws + 8 * MB);
    bf16* W1Tc   = (bf16*)(ws + 8 * MB);
    bf16* W2Tc   = (bf16*)(ws + 10 * MB);
    bf16* gchunk = (bf16*)(ws + 12 * MB);
    bf16* kbuf   = (bf16*)(ws + 16 * MB);
    bf16* vtbuf  = (bf16*)(ws + 24 * MB);
    float* hbuf  = (float*)(ws + 16 * MB);
    bf16* WqT    = (bf16*)(ws + 32 * MB);
    bf16* WkT    = (bf16*)(ws + 34 * MB);
    bf16* WvT    = (bf16*)(ws + 36 * MB);
    bf16* WoT    = (bf16*)(ws + 38 * MB);
    float* outacc = (float*)(ws + 40 * MB);

    transpose2<<<dim3(2, 32, 16), tb, 0, stream>>>(Wq, HB, 64, WqT, HB, 1024);
    transpose2<<<dim3(2, 32, 16), tb, 0, stream>>>(Wk, HB, 64, WkT, HB, 1024);
    transpose2<<<dim3(2, 32, 16), tb, 0, stream>>>(Wv, HB, 64, WvT, HB, 1024);
    transpose2<<<dim3(32, 32, 1), tb, 0, stream>>>(Wo, 0, 1024, WoT, 0, 1024);
    ln_rows<<<4096, 256, 0, stream>>>(hidden, ln1g, ln1b, x1);
    qkv_pipe<<<dim3(8, 32, 3), 256, 0, stream>>>(x1, WqT, WkT, WvT, bq, bk, bv,
                                                 qbuf, kbuf, vtbuf);
    attn_flash<<<512, 512, 0, stream>>>(qbuf, kbuf, vtbuf, mask, attnC);
    pipe128<EPI_WO, 1024, 3><<<dim3(8, 32), 256, 0, stream>>>(attnC, WoT, bo, 1024,
                                                              hidden, nullptr, nullptr, hbuf);
    ln_rows<<<4096, 256, 0, stream>>>(hbuf, ln2g, ln2b, x2);

    for (int c = 0; c < 8; c++) {
      transpose2<<<dim3(16, 32, 1), tb, 0, stream>>>(W1 + c * 512, 0, 4096,
                                                     W1Tc, 0, 1024);
      transpose2<<<dim3(32, 16, 1), tb, 0, stream>>>(W2 + (size_t)c * 512 * 1024, 0, 1024,
                                                     W2Tc, 0, 512);
      gemm_bt<EPI_GELU, 1024><<<dim3(4, 32), 256, 0, stream>>>(x2, W1Tc, b1 + c * 512, 512,
                                                               nullptr, nullptr, gchunk, nullptr);
      if (c == 0)
        gemm_bt<EPI_ACC0, 512><<<dim3(8, 32), 256, 0, stream>>>(gchunk, W2Tc, b2, 1024,
                                                                nullptr, outacc, nullptr, nullptr);
      else if (c < 7)
        gemm_bt<EPI_ACC, 512><<<dim3(8, 32), 256, 0, stream>>>(gchunk, W2Tc, b2, 1024,
                                                               nullptr, outacc, nullptr, nullptr);
      else
        gemm_bt<EPI_FINAL, 512><<<dim3(8, 32), 256, 0, stream>>>(gchunk, W2Tc, b2, 1024,
                                                                 hbuf, outacc, nullptr, out);
    }
  }

  (void)in_sizes; (void)n_in; (void)out_size;
}

// Round 16
// 222.861 us; speedup vs baseline: 1.3727x; 1.0383x over previous
//
#include <hip/hip_runtime.h>

typedef __bf16 bf16;
typedef __bf16 bf16x4 __attribute__((ext_vector_type(4)));
typedef __bf16 bf16x8 __attribute__((ext_vector_type(8)));
typedef float  f32x4  __attribute__((ext_vector_type(4)));

#define F32X4_ZERO ((f32x4){0.f, 0.f, 0.f, 0.f})

__device__ __forceinline__ f32x4 mfma16(bf16x8 a, bf16x8 b, f32x4 c) {
  return __builtin_amdgcn_mfma_f32_16x16x32_bf16(a, b, c, 0, 0, 0);
}

__device__ __forceinline__ void gld16(const void* g, void* l) {
  __builtin_amdgcn_global_load_lds((const __attribute__((address_space(1))) void*)g,
                                   (__attribute__((address_space(3))) void*)l, 16, 0, 0);
}

__device__ __forceinline__ float gelu_f(float u) {
  return 0.5f * u * (1.0f + erff(u * 0.70710678118654752f));
}

// ---- BK=64 tile helpers (attention + chunked-path engine) ----
__device__ __forceinline__ bf16x8 frag_ld(const bf16* base, int row, int c16) {
  return *(const bf16x8*)((const char*)base + row * 128 + (((c16) ^ (row & 7)) << 4));
}

// ---- BK=32 tile helpers (counted-vmcnt pipeline engine) ----
// row = 64B; chunk = 1KB = 16 rows. phys slot = c16 ^ ((row>>1)&3)  (2-way free).
__device__ __forceinline__ bf16x8 frag_ld32(const bf16* base, int row, int c16) {
  return *(const bf16x8*)((const char*)base + row * 64 + ((c16 ^ ((row >> 1) & 3)) << 4));
}
#define WAITB(N) asm volatile("s_waitcnt vmcnt(" #N ")\ns_barrier" ::: "memory")

// ---------------------------------------------------------------- transpose
__global__ void transpose2(const float* __restrict__ src, size_t sBatch, int sStride,
                           bf16* __restrict__ dst, size_t dBatch, int dStride) {
  __shared__ bf16 t[32][33];
  src += (size_t)blockIdx.z * sBatch;
  dst += (size_t)blockIdx.z * dBatch;
  int c0 = blockIdx.x * 32, r0 = blockIdx.y * 32;
#pragma unroll
  for (int i = 0; i < 4; i++) {
    int r = threadIdx.y + i * 8;
    t[r][threadIdx.x] = (bf16)src[(size_t)(r0 + r) * sStride + c0 + threadIdx.x];
  }
  __syncthreads();
#pragma unroll
  for (int i = 0; i < 4; i++) {
    int c = threadIdx.y + i * 8;
    dst[(size_t)(c0 + c) * dStride + r0 + threadIdx.x] = t[threadIdx.x][c];
  }
}

// ---------------------------------------------------------------- layernorm
__global__ __launch_bounds__(256) void ln_rows(const float* __restrict__ in,
                                               const float* __restrict__ gam,
                                               const float* __restrict__ bet,
                                               bf16* __restrict__ out) {
  int row = blockIdx.x, tid = threadIdx.x;
  f32x4 x = *(const f32x4*)(in + (size_t)row * 1024 + tid * 4);
  float s = 0.f, q = 0.f;
#pragma unroll
  for (int j = 0; j < 4; j++) { s += x[j]; q += x[j] * x[j]; }
#pragma unroll
  for (int o = 1; o < 64; o <<= 1) {
    s += __shfl_xor(s, o, 64);
    q += __shfl_xor(q, o, 64);
  }
  __shared__ float red[8];
  if ((tid & 63) == 0) { red[(tid >> 6) * 2] = s; red[(tid >> 6) * 2 + 1] = q; }
  __syncthreads();
  s = red[0] + red[2] + red[4] + red[6];
  q = red[1] + red[3] + red[5] + red[7];
  float mean = s * (1.f / 1024.f);
  float var  = q * (1.f / 1024.f) - mean * mean;
  float inv  = rsqrtf(var + 1e-6f);
  bf16x4 o;
#pragma unroll
  for (int j = 0; j < 4; j++) {
    int c = tid * 4 + j;
    o[j] = (bf16)((x[j] - mean) * inv * gam[c] + bet[c]);
  }
  *(bf16x4*)(out + (size_t)row * 1024 + tid * 4) = o;
}

// ============================================================ pipe engines
enum { EPI_WO = 0, EPI_GELU = 1, EPI_ACC0 = 2, EPI_ACC = 3, EPI_FINAL = 4 };

// ---------------------------------------------------------------- 256x128 pipe (FFN1)
// BM=256, BN=128, BK=32, 8 waves (4Mx2N), 3-slot LDS (72KB -> 2 blocks/CU),
// depth-2 prefetch, counted vmcnt(3/0), conflict-free swizzle.
// Grid 512 flat; XCD rect: each XCD = 4 M-tiles x 16 N-tiles (A 2MB + B 4MB).
__global__ __launch_bounds__(512) void pipe256x128_gelu(
    const bf16* __restrict__ A, const bf16* __restrict__ BT, const float* __restrict__ bias,
    int N, bf16* __restrict__ outb) {
  int tid = threadIdx.x, lane = tid & 63, wv = tid >> 6;  // 8 waves
  int bid = blockIdx.x;
  int xcd = bid & 7, idx = bid >> 3;          // idx 0..63
  int mg = xcd >> 1, ng = xcd & 1;
  int m0 = (mg * 4 + (idx >> 4)) * 256;       // 16 M-tiles total
  int n0 = (ng * 16 + (idx & 15)) * 128;      // 32 N-tiles total
  int wrow = (wv >> 1) * 64, wcol = (wv & 1) * 64;
  __shared__ __align__(16) bf16 lds[3][12288];  // slot 24KB: A 16KB + B 8KB
  f32x4 acc[4][4];
#pragma unroll
  for (int a = 0; a < 4; a++)
#pragma unroll
    for (int n = 0; n < 4; n++) acc[a][n] = F32X4_ZERO;

  constexpr int K = 1024, nk = K / 32;
  int rin = lane >> 2;
  int sbc = ((lane & 3) ^ ((lane >> 3) & 3)) * 16;
  auto stage = [&](int slot, int k0) {
#pragma unroll
    for (int j = 0; j < 3; j++) {
      int c = wv * 3 + j;                     // 0..23: 16 A chunks + 8 B chunks
      if (c < 16)
        gld16((const char*)A + ((size_t)(m0 + c * 16 + rin) * K + k0) * 2 + sbc,
              (char*)lds[slot] + c * 1024);
      else
        gld16((const char*)BT + ((size_t)(n0 + (c - 16) * 16 + rin) * K + k0) * 2 + sbc,
              (char*)lds[slot] + c * 1024);
    }
  };

  stage(0, 0); stage(1, 32);
#pragma unroll 1
  for (int t = 0; t < nk; t++) {
    if (t < nk - 1) WAITB(3);   // stage(t) landed; stage(t+1) stays in flight
    else            WAITB(0);
    if (t + 2 < nk) stage((t + 2) % 3, (t + 2) * 32);
    const bf16* As = lds[t % 3];
    const bf16* Bs = lds[t % 3] + 8192;       // B after 16KB of A
    int c16 = lane >> 4;
    bf16x8 af[4], bfr[4];
#pragma unroll
    for (int mf = 0; mf < 4; mf++)
      af[mf] = frag_ld32(As, wrow + mf * 16 + (lane & 15), c16);
#pragma unroll
    for (int nf = 0; nf < 4; nf++)
      bfr[nf] = frag_ld32(Bs, wcol + nf * 16 + (lane & 15), c16);
#pragma unroll
    for (int mf = 0; mf < 4; mf++)
#pragma unroll
      for (int nf = 0; nf < 4; nf++)
        acc[mf][nf] = mfma16(af[mf], bfr[nf], acc[mf][nf]);
  }
#pragma unroll
  for (int mf = 0; mf < 4; mf++)
#pragma unroll
    for (int nf = 0; nf < 4; nf++)
#pragma unroll
      for (int i = 0; i < 4; i++) {
        int row = m0 + wrow + mf * 16 + ((lane >> 4) << 2) + i;
        int col = n0 + wcol + nf * 16 + (lane & 15);
        outb[(size_t)row * N + col] = (bf16)gelu_f(acc[mf][nf][i] + bias[col]);
      }
}

// ---------------------------------------------------------------- 128^2 pipe
// 128x128 tile, BK=32, 3-slot LDS (48KB -> 3 blocks/CU), depth-2 prefetch,
// counted vmcnt(4/0) + raw barrier, conflict-free swizzle.
template <int EPI, int K, int NTL>   // NTL: log2(#n-tiles per XCD group)
__global__ __launch_bounds__(256) void pipe128(
    const bf16* __restrict__ A, const bf16* __restrict__ BT, const float* __restrict__ bias,
    int N,
    const float* __restrict__ resid, float* __restrict__ facc,
    bf16* __restrict__ outb, float* __restrict__ outf) {
  int tid = threadIdx.x, lane = tid & 63, wv = tid >> 6;
  int bid = blockIdx.x + (blockIdx.y << 3);
  int xcd = bid & 7, idx = bid >> 3;
  int m0 = (xcd * 4 + (idx >> NTL)) * 128;
  int n0 = (idx & ((1 << NTL) - 1)) * 128;
  int wrow = (wv >> 1) * 64, wcol = (wv & 1) * 64;
  __shared__ __align__(16) bf16 lds[3][8192];  // slot 16KB: A 8KB + B 8KB
  f32x4 acc[4][4];
#pragma unroll
  for (int a = 0; a < 4; a++)
#pragma unroll
    for (int n = 0; n < 4; n++) acc[a][n] = F32X4_ZERO;

  constexpr int nk = K / 32;
  int rin = lane >> 2;
  int sbc = ((lane & 3) ^ ((lane >> 3) & 3)) * 16;
  auto stage = [&](int slot, int k0) {
#pragma unroll
    for (int j = 0; j < 4; j++) {
      int c = wv * 4 + j;                           // 0..15
      if (c < 8)
        gld16((const char*)A + ((size_t)(m0 + c * 16 + rin) * K + k0) * 2 + sbc,
              (char*)lds[slot] + c * 1024);
      else
        gld16((const char*)BT + ((size_t)(n0 + (c - 8) * 16 + rin) * K + k0) * 2 + sbc,
              (char*)lds[slot] + c * 1024);
    }
  };

  stage(0, 0); stage(1, 32);
#pragma unroll 1
  for (int t = 0; t < nk; t++) {
    if (t < nk - 1) WAITB(4);
    else            WAITB(0);
    if (t + 2 < nk) stage((t + 2) % 3, (t + 2) * 32);
    const bf16* As = lds[t % 3];
    const bf16* Bs = lds[t % 3] + 4096;
    int c16 = lane >> 4;
    bf16x8 af[4], bfr[4];
#pragma unroll
    for (int mf = 0; mf < 4; mf++)
      af[mf] = frag_ld32(As, wrow + mf * 16 + (lane & 15), c16);
#pragma unroll
    for (int nf = 0; nf < 4; nf++)
      bfr[nf] = frag_ld32(Bs, wcol + nf * 16 + (lane & 15), c16);
#pragma unroll
    for (int mf = 0; mf < 4; mf++)
#pragma unroll
      for (int nf = 0; nf < 4; nf++)
        acc[mf][nf] = mfma16(af[mf], bfr[nf], acc[mf][nf]);
  }
#pragma unroll
  for (int mf = 0; mf < 4; mf++)
#pragma unroll
    for (int nf = 0; nf < 4; nf++)
#pragma unroll
      for (int i = 0; i < 4; i++) {
        int row = m0 + wrow + mf * 16 + ((lane >> 4) << 2) + i;
        int col = n0 + wcol + nf * 16 + (lane & 15);
        size_t idx2 = (size_t)row * N + col;
        float v = acc[mf][nf][i];
        if constexpr (EPI == EPI_WO) {
          outf[idx2] = v + bias[col] + resid[idx2];
        } else if constexpr (EPI == EPI_GELU) {
          outb[idx2] = (bf16)gelu_f(v + bias[col]);
        } else if constexpr (EPI == EPI_ACC0) {
          facc[idx2] = v;
        } else if constexpr (EPI == EPI_ACC) {
          facc[idx2] += v;
        } else {
          outf[idx2] = facc[idx2] + v + bias[col] + resid[idx2];
        }
      }
}

// ---------------------------------------------------------------- QKV pipe
__global__ __launch_bounds__(256) void qkv_pipe(
    const bf16* __restrict__ x1,
    const bf16* __restrict__ WqT, const bf16* __restrict__ WkT, const bf16* __restrict__ WvT,
    const float* __restrict__ bq, const float* __restrict__ bk, const float* __restrict__ bv,
    bf16* __restrict__ qo, bf16* __restrict__ ko, bf16* __restrict__ vto) {
  int tid = threadIdx.x, lane = tid & 63, wv = tid >> 6;
  int z = blockIdx.z;
  const bf16* BT; const float* bias;
  if (z == 0)      { BT = WqT; bias = bq; }
  else if (z == 1) { BT = WkT; bias = bk; }
  else             { BT = WvT; bias = bv; }
  int bid = blockIdx.x + (blockIdx.y << 3);
  int xcd = bid & 7, idx = bid >> 3;
  int m0 = (xcd * 4 + (idx >> 3)) * 128, n0 = (idx & 7) * 128;
  int wrow = (wv >> 1) * 64, wcol = (wv & 1) * 64;
  __shared__ __align__(16) bf16 lds[3][8192];
  f32x4 acc[4][4];
#pragma unroll
  for (int a = 0; a < 4; a++)
#pragma unroll
    for (int n = 0; n < 4; n++) acc[a][n] = F32X4_ZERO;

  constexpr int K = 1024, nk = K / 32;
  int rin = lane >> 2;
  int sbc = ((lane & 3) ^ ((lane >> 3) & 3)) * 16;
  auto stage = [&](int slot, int k0) {
#pragma unroll
    for (int j = 0; j < 4; j++) {
      int c = wv * 4 + j;
      if (c < 8)
        gld16((const char*)x1 + ((size_t)(m0 + c * 16 + rin) * K + k0) * 2 + sbc,
              (char*)lds[slot] + c * 1024);
      else
        gld16((const char*)BT + ((size_t)(n0 + (c - 8) * 16 + rin) * K + k0) * 2 + sbc,
              (char*)lds[slot] + c * 1024);
    }
  };

  stage(0, 0); stage(1, 32);
#pragma unroll 1
  for (int t = 0; t < nk; t++) {
    if (t < nk - 1) WAITB(4);
    else            WAITB(0);
    if (t + 2 < nk) stage((t + 2) % 3, (t + 2) * 32);
    const bf16* As = lds[t % 3];
    const bf16* Bs = lds[t % 3] + 4096;
    int c16 = lane >> 4;
    bf16x8 af[4], bfr[4];
#pragma unroll
    for (int mf = 0; mf < 4; mf++)
      af[mf] = frag_ld32(As, wrow + mf * 16 + (lane & 15), c16);
#pragma unroll
    for (int nf = 0; nf < 4; nf++)
      bfr[nf] = frag_ld32(Bs, wcol + nf * 16 + (lane & 15), c16);
#pragma unroll
    for (int mf = 0; mf < 4; mf++)
#pragma unroll
      for (int nf = 0; nf < 4; nf++)
        acc[mf][nf] = mfma16(af[mf], bfr[nf], acc[mf][nf]);
  }
#pragma unroll
  for (int mf = 0; mf < 4; mf++)
#pragma unroll
    for (int nf = 0; nf < 4; nf++)
#pragma unroll
      for (int i = 0; i < 4; i++) {
        int row  = m0 + wrow + mf * 16 + ((lane >> 4) << 2) + i;
        int ncol = n0 + wcol + nf * 16 + (lane & 15);
        int bb = row >> 10, s = row & 1023, head = ncol >> 6, d = ncol & 63;
        size_t bh = (size_t)bb * 16 + head;
        float v = acc[mf][nf][i] + bias[ncol];
        if (z == 0)      qo[(bh * 1024 + s) * 64 + d] = (bf16)(v * 0.125f);
        else if (z == 1) ko[(bh * 1024 + s) * 64 + d] = (bf16)v;
        else             vto[(bh * 64 + d) * 1024 + s] = (bf16)v;
      }
}

// ---------------------------------------------------------------- attention
__global__ __launch_bounds__(512) void attn_flash(
    const bf16* __restrict__ qb, const bf16* __restrict__ kb, const bf16* __restrict__ vtb,
    const int* __restrict__ mask, bf16* __restrict__ attnC) {
  int tid = threadIdx.x, lane = tid & 63, wv = tid >> 6;
  int wgid = blockIdx.x;
  int nid  = (wgid & 7) * 64 + (wgid >> 3);
  int qblk = nid & 7, h = (nid >> 3) & 15, b = nid >> 7;
  int qrow0 = qblk * 128 + wv * 16;

  __shared__ float smask[1024];
  __shared__ __align__(16) bf16 kt[2][64 * 64];
  __shared__ __align__(16) bf16 vt[2][64 * 64];
  __shared__ __align__(16) bf16 pb[8][16][72];
  for (int i = tid; i < 1024; i += 512) smask[i] = mask[b * 1024 + i] ? 0.f : -1e9f;

  size_t bh = (size_t)b * 16 + h;
  const bf16* qp = qb + (bh * 1024 + qrow0) * 64;
  bf16x8 qa[2];
#pragma unroll
  for (int kc = 0; kc < 2; kc++)
    qa[kc] = *(const bf16x8*)(qp + (lane & 15) * 64 + kc * 32 + (lane >> 4) * 8);

  const bf16* kp = kb + bh * 1024 * 64;
  const bf16* vp = vtb + bh * 64 * 1024;
  bf16* myp = &pb[wv][0][0];

  bf16x8 vone;
#pragma unroll
  for (int j = 0; j < 8; j++) vone[j] = (bf16)1.0f;

  f32x4 ssum = F32X4_ZERO;
  f32x4 oacc[4];
#pragma unroll
  for (int i = 0; i < 4; i++) oacc[i] = F32X4_ZERO;

  int srl = lane >> 3;
  int sbc = ((lane & 7) ^ srl) * 16;
  auto stage = [&](int buf, int t2) {
    int key0n = t2 * 64;
#pragma unroll
    for (int j = 0; j < 2; j++) {
      int c = wv * 2 + j;
      if (c < 8) {
        int row = c * 8 + srl;
        gld16((const char*)kp + ((size_t)(key0n + row) * 64) * 2 + sbc,
              (char*)kt[buf] + c * 1024);
      } else {
        int row = (c - 8) * 8 + srl;
        gld16((const char*)vp + ((size_t)row * 1024 + key0n) * 2 + sbc,
              (char*)vt[buf] + (c - 8) * 1024);
      }
    }
  };

  stage(0, 0);
  __syncthreads();

  for (int t = 0; t < 16; t++) {
    int cur = t & 1;
    if (t < 15) stage(cur ^ 1, t + 1);
    const bf16* kcur = kt[cur];
    const bf16* vcur = vt[cur];
    int key0 = t * 64;
    f32x4 st[4];
    __builtin_amdgcn_s_setprio(1);
#pragma unroll
    for (int nt = 0; nt < 4; nt++) {
      st[nt] = F32X4_ZERO;
#pragma unroll
      for (int kc = 0; kc < 2; kc++) {
        bf16x8 kf = frag_ld(kcur, nt * 16 + (lane & 15), kc * 4 + (lane >> 4));
        st[nt] = mfma16(qa[kc], kf, st[nt]);
      }
    }
    __builtin_amdgcn_s_setprio(0);
#pragma unroll
    for (int nt = 0; nt < 4; nt++) {
      float ms = smask[key0 + nt * 16 + (lane & 15)] - 8.0f;
#pragma unroll
      for (int i = 0; i < 4; i++) st[nt][i] = __expf(st[nt][i] + ms);
    }
#pragma unroll
    for (int nt = 0; nt < 4; nt++)
#pragma unroll
      for (int i = 0; i < 4; i++)
        myp[((lane >> 4) * 4 + i) * 72 + nt * 16 + (lane & 15)] = (bf16)st[nt][i];
    __builtin_amdgcn_s_setprio(1);
#pragma unroll
    for (int kc = 0; kc < 2; kc++) {
      bf16x8 pa = *(const bf16x8*)(myp + (lane & 15) * 72 + kc * 32 + (lane >> 4) * 8);
      ssum = mfma16(pa, vone, ssum);
#pragma unroll
      for (int dn = 0; dn < 4; dn++) {
        bf16x8 vf = frag_ld(vcur, dn * 16 + (lane & 15), kc * 4 + (lane >> 4));
        oacc[dn] = mfma16(pa, vf, oacc[dn]);
      }
    }
    __builtin_amdgcn_s_setprio(0);
    __syncthreads();
  }
#pragma unroll
  for (int i = 0; i < 4; i++) {
    float inv = 1.0f / ssum[i];
    int row = qrow0 + ((lane >> 4) << 2) + i;
#pragma unroll
    for (int dn = 0; dn < 4; dn++)
      attnC[(size_t)(b * 1024 + row) * 1024 + h * 64 + dn * 16 + (lane & 15)] =
          (bf16)(oacc[dn][i] * inv);
  }
}

// ---------------------------------------------------------------- old 128^2 (chunked path only)
template <int EPI, int K>
__global__ __launch_bounds__(256) void gemm_bt(
    const bf16* __restrict__ A, const bf16* __restrict__ BT, const float* __restrict__ bias,
    int N,
    const float* __restrict__ resid, float* __restrict__ facc,
    bf16* __restrict__ outb, float* __restrict__ outf) {
  int tid = threadIdx.x, lane = tid & 63, wv = tid >> 6;
  int m0 = blockIdx.y * 128, n0 = blockIdx.x * 128;
  int wrow = (wv >> 1) * 64, wcol = (wv & 1) * 64;
  __shared__ __align__(16) bf16 lA[2][128 * 64];
  __shared__ __align__(16) bf16 lB[2][128 * 64];
  f32x4 acc[4][4];
#pragma unroll
  for (int a = 0; a < 4; a++)
#pragma unroll
    for (int n = 0; n < 4; n++) acc[a][n] = F32X4_ZERO;

  int cbs = ((lane & 7) ^ (lane >> 3)) * 16;
  auto stage = [&](int buf, int k0) {
#pragma unroll
    for (int s = 0; s < 4; s++) {
      int c = s * 4 + wv;
      int row = c * 8 + (lane >> 3);
      gld16((const char*)A  + ((size_t)(m0 + row) * K + k0) * 2 + cbs,
            (char*)lA[buf] + c * 1024);
      gld16((const char*)BT + ((size_t)(n0 + row) * K + k0) * 2 + cbs,
            (char*)lB[buf] + c * 1024);
    }
  };

  constexpr int nk = K >> 6;
  stage(0, 0);
  __syncthreads();
#pragma unroll 1
  for (int t = 0; t < nk; t++) {
    int cur = t & 1;
    if (t + 1 < nk) stage(cur ^ 1, (t + 1) * 64);
#pragma unroll
    for (int kc = 0; kc < 2; kc++) {
      int c16 = kc * 4 + (lane >> 4);
      bf16x8 af[4], bfr[4];
#pragma unroll
      for (int mf = 0; mf < 4; mf++)
        af[mf] = frag_ld(lA[cur], wrow + mf * 16 + (lane & 15), c16);
#pragma unroll
      for (int nf = 0; nf < 4; nf++)
        bfr[nf] = frag_ld(lB[cur], wcol + nf * 16 + (lane & 15), c16);
#pragma unroll
      for (int mf = 0; mf < 4; mf++)
#pragma unroll
        for (int nf = 0; nf < 4; nf++)
          acc[mf][nf] = mfma16(af[mf], bfr[nf], acc[mf][nf]);
    }
    __syncthreads();
  }
#pragma unroll
  for (int mf = 0; mf < 4; mf++)
#pragma unroll
    for (int nf = 0; nf < 4; nf++)
#pragma unroll
      for (int i = 0; i < 4; i++) {
        int row = m0 + wrow + mf * 16 + ((lane >> 4) << 2) + i;
        int col = n0 + wcol + nf * 16 + (lane & 15);
        size_t idx2 = (size_t)row * N + col;
        float v = acc[mf][nf][i];
        if constexpr (EPI == EPI_WO) {
          outf[idx2] = v + bias[col] + resid[idx2];
        } else if constexpr (EPI == EPI_GELU) {
          outb[idx2] = (bf16)gelu_f(v + bias[col]);
        } else if constexpr (EPI == EPI_ACC0) {
          facc[idx2] = v;
        } else if constexpr (EPI == EPI_ACC) {
          facc[idx2] += v;
        } else {
          outf[idx2] = facc[idx2] + v + bias[col] + resid[idx2];
        }
      }
}

// ---------------------------------------------------------------- launch
extern "C" void kernel_launch(void* const* d_in, const int* in_sizes, int n_in,
                              void* d_out, int out_size, void* d_ws, size_t ws_size,
                              hipStream_t stream) {
  const float* hidden = (const float*)d_in[0];
  const int*   mask   = (const int*)d_in[1];
  const float* Wq = (const float*)d_in[2];
  const float* bq = (const float*)d_in[3];
  const float* Wk = (const float*)d_in[4];
  const float* bk = (const float*)d_in[5];
  const float* Wv = (const float*)d_in[6];
  const float* bv = (const float*)d_in[7];
  const float* Wo = (const float*)d_in[8];
  const float* bo = (const float*)d_in[9];
  const float* ln1g = (const float*)d_in[10];
  const float* ln1b = (const float*)d_in[11];
  const float* ln2g = (const float*)d_in[12];
  const float* ln2b = (const float*)d_in[13];
  const float* W1 = (const float*)d_in[14];
  const float* b1 = (const float*)d_in[15];
  const float* W2 = (const float*)d_in[16];
  const float* b2 = (const float*)d_in[17];
  float* out = (float*)d_out;

  char* ws = (char*)d_ws;
  const size_t MB = 1ull << 20;
  dim3 tb(32, 8);
  const size_t HB = 64 * 1024;

  if (ws_size >= 96 * MB) {
    // ---------------- simple path (88 MB) ----------------
    bf16* x1    = (bf16*)(ws + 0 * MB);
    bf16* attnC = x1;
    bf16* x2    = x1;
    bf16* qbuf  = (bf16*)(ws + 8 * MB);
    bf16* W1T   = qbuf;
    bf16* kbuf  = (bf16*)(ws + 16 * MB);
    bf16* W2T   = kbuf;
    bf16* vtbuf = (bf16*)(ws + 24 * MB);
    float* hbuf = (float*)(ws + 32 * MB);
    bf16* WqT   = (bf16*)(ws + 48 * MB);
    bf16* WkT   = (bf16*)(ws + 50 * MB);
    bf16* WvT   = (bf16*)(ws + 52 * MB);
    bf16* WoT   = (bf16*)(ws + 54 * MB);
    bf16* gbuf  = (bf16*)(ws + 56 * MB);

    transpose2<<<dim3(2, 32, 16), tb, 0, stream>>>(Wq, HB, 64, WqT, HB, 1024);
    transpose2<<<dim3(2, 32, 16), tb, 0, stream>>>(Wk, HB, 64, WkT, HB, 1024);
    transpose2<<<dim3(2, 32, 16), tb, 0, stream>>>(Wv, HB, 64, WvT, HB, 1024);
    transpose2<<<dim3(32, 32, 1), tb, 0, stream>>>(Wo, 0, 1024, WoT, 0, 1024);
    ln_rows<<<4096, 256, 0, stream>>>(hidden, ln1g, ln1b, x1);
    qkv_pipe<<<dim3(8, 32, 3), 256, 0, stream>>>(x1, WqT, WkT, WvT, bq, bk, bv,
                                                 qbuf, kbuf, vtbuf);
    attn_flash<<<512, 512, 0, stream>>>(qbuf, kbuf, vtbuf, mask, attnC);
    pipe128<EPI_WO, 1024, 3><<<dim3(8, 32), 256, 0, stream>>>(attnC, WoT, bo, 1024,
                                                              hidden, nullptr, nullptr, hbuf);
    ln_rows<<<4096, 256, 0, stream>>>(hbuf, ln2g, ln2b, x2);
    transpose2<<<dim3(128, 32, 1), tb, 0, stream>>>(W1, 0, 4096, W1T, 0, 1024);
    transpose2<<<dim3(32, 128, 1), tb, 0, stream>>>(W2, 0, 1024, W2T, 0, 4096);
    pipe256x128_gelu<<<512, 512, 0, stream>>>(x2, W1T, b1, 4096, gbuf);
    pipe128<EPI_WO, 4096, 3><<<dim3(8, 32), 256, 0, stream>>>(gbuf, W2T, b2, 1024,
                                                              hbuf, nullptr, nullptr, out);
  } else {
    // ---------------- chunked path (56 MB, old engine) ----------------
    bf16* x1     = (bf16*)(ws + 0 * MB);
    bf16* attnC  = x1;
    bf16* x2     = x1;
    bf16* qbuf   = (bf16*)(ws + 8 * MB);
    bf16* W1Tc   = (bf16*)(ws + 8 * MB);
    bf16* W2Tc   = (bf16*)(ws + 10 * MB);
    bf16* gchunk = (bf16*)(ws + 12 * MB);
    bf16* kbuf   = (bf16*)(ws + 16 * MB);
    bf16* vtbuf  = (bf16*)(ws + 24 * MB);
    float* hbuf  = (float*)(ws + 16 * MB);
    bf16* WqT    = (bf16*)(ws + 32 * MB);
    bf16* WkT    = (bf16*)(ws + 34 * MB);
    bf16* WvT    = (bf16*)(ws + 36 * MB);
    bf16* WoT    = (bf16*)(ws + 38 * MB);
    float* outacc = (float*)(ws + 40 * MB);

    transpose2<<<dim3(2, 32, 16), tb, 0, stream>>>(Wq, HB, 64, WqT, HB, 1024);
    transpose2<<<dim3(2, 32, 16), tb, 0, stream>>>(Wk, HB, 64, WkT, HB, 1024);
    transpose2<<<dim3(2, 32, 16), tb, 0, stream>>>(Wv, HB, 64, WvT, HB, 1024);
    transpose2<<<dim3(32, 32, 1), tb, 0, stream>>>(Wo, 0, 1024, WoT, 0, 1024);
    ln_rows<<<4096, 256, 0, stream>>>(hidden, ln1g, ln1b, x1);
    qkv_pipe<<<dim3(8, 32, 3), 256, 0, stream>>>(x1, WqT, WkT, WvT, bq, bk, bv,
                                                 qbuf, kbuf, vtbuf);
    attn_flash<<<512, 512, 0, stream>>>(qbuf, kbuf, vtbuf, mask, attnC);
    pipe128<EPI_WO, 1024, 3><<<dim3(8, 32), 256, 0, stream>>>(attnC, WoT, bo, 1024,
                                                              hidden, nullptr, nullptr, hbuf);
    ln_rows<<<4096, 256, 0, stream>>>(hbuf, ln2g, ln2b, x2);

    for (int c = 0; c < 8; c++) {
      transpose2<<<dim3(16, 32, 1), tb, 0, stream>>>(W1 + c * 512, 0, 4096,
                                                     W1Tc, 0, 1024);
      transpose2<<<dim3(32, 16, 1), tb, 0, stream>>>(W2 + (size_t)c * 512 * 1024, 0, 1024,
                                                     W2Tc, 0, 512);
      gemm_bt<EPI_GELU, 1024><<<dim3(4, 32), 256, 0, stream>>>(x2, W1Tc, b1 + c * 512, 512,
                                                               nullptr, nullptr, gchunk, nullptr);
      if (c == 0)
        gemm_bt<EPI_ACC0, 512><<<dim3(8, 32), 256, 0, stream>>>(gchunk, W2Tc, b2, 1024,
                                                                nullptr, outacc, nullptr, nullptr);
      else if (c < 7)
        gemm_bt<EPI_ACC, 512><<<dim3(8, 32), 256, 0, stream>>>(gchunk, W2Tc, b2, 1024,
                                                               nullptr, outacc, nullptr, nullptr);
      else
        gemm_bt<EPI_FINAL, 512><<<dim3(8, 32), 256, 0, stream>>>(gchunk, W2Tc, b2, 1024,
                                                                 hbuf, outacc, nullptr, out);
    }
  }

  (void)in_sizes; (void)n_in; (void)out_size;
}